// Round 15
// baseline (137.441 us; speedup 1.0000x reference)
//
#include <hip/hip_runtime.h>
#include <hip/hip_bf16.h>
#include <stdint.h>

// Problem constants: B=2, L=2048, D=1024, H=16, hd=64, scale=1/8 (log2e-folded).

typedef __bf16 bf16x8 __attribute__((ext_vector_type(8)));
typedef float f32x4 __attribute__((ext_vector_type(4)));

__device__ __forceinline__ unsigned short f2bf(float f) {
  union { float f; unsigned int u; } v; v.f = f;
  unsigned int r = v.u + 0x7FFFu + ((v.u >> 16) & 1u);  // RNE
  return (unsigned short)(r >> 16);
}
__device__ __forceinline__ float b2f(unsigned short u) {
  union { unsigned int u; float f; } v; v.u = ((unsigned int)u) << 16;
  return v.f;
}

__device__ __forceinline__ void gl2lds16(const void* gptr, void* lptr) {
  __builtin_amdgcn_global_load_lds(
      (const __attribute__((address_space(1))) unsigned int*)gptr,
      (__attribute__((address_space(3))) unsigned int*)lptr, 16, 0, 0);
}

// ------- fp32 -> bf16 conversion (x | W_qkv | W_out) + RoPE cos/sin table ---
__global__ void cvt_all(const float4* __restrict__ x,
                        const float4* __restrict__ wq,
                        const float4* __restrict__ wo,
                        ushort4* __restrict__ xb,
                        ushort4* __restrict__ wqb,
                        ushort4* __restrict__ wob,
                        float2* __restrict__ tab) {
  int i = blockIdx.x * 256 + threadIdx.x;
  if (i >= 2097152) {
    int t = i - 2097152;         // 0..65535 = l*32 + fi
    int l = t >> 5, fi = t & 31;
    float inv_freq = powf(10000.0f, -(float)fi / 32.0f);
    float s, c;
    sincosf((float)l * inv_freq, &s, &c);
    tab[t] = make_float2(c, s);
    return;
  }
  float4 v; ushort4* dst; int j;
  if (i < 1048576)      { v = x[i];            dst = xb;  j = i; }
  else if (i < 1835008) { v = wq[i - 1048576]; dst = wqb; j = i - 1048576; }
  else                  { v = wo[i - 1835008]; dst = wob; j = i - 1835008; }
  ushort4 o;
  o.x = f2bf(v.x); o.y = f2bf(v.y); o.z = f2bf(v.z); o.w = f2bf(v.w);
  dst[j] = o;
}

// ---------------- GEMM1 + fused RoPE/scatter epilogue -----------------------
// 128m x 64n tiles -> grid 1536 flat = 6 blocks/CU (24KB LDS dbuf), double
// the sync domains of the old 128x128/768-block version (which sat at 3/CU,
// all pipes <17%). Flat blockIdx XCD-chunked: xcd = bid&7 owns an
// 8-mtile x 24-ntile region (A 2MB + B 3MB ~ L2-resident) to cut the 3x
// FETCH inflation from round-robin dispatch. Per K-step per wave (32m x 64n):
// 2 A-frags + 4 B-frags (conflict-free swizzle, r14) + 8 MFMA.
__global__ __launch_bounds__(256) void gemm1_fused(
    const __hip_bfloat16* __restrict__ A,
    const __hip_bfloat16* __restrict__ B,
    unsigned short* __restrict__ Qs,
    unsigned short* __restrict__ Ks,
    unsigned short* __restrict__ Vt,
    const float2* __restrict__ tab, int K) {
  __shared__ __align__(16) char lds[24576];  // buf: [0,8K) A, [8K,12K) B; x2
  const int tid = threadIdx.x;
  const int lane = tid & 63;
  const int w = tid >> 6;
  const int g = lane >> 4, lr = lane & 15;
  // XCD-chunked flat grid: 1536 blocks; xcd region = 8 mtiles x 24 ntiles.
  const int bid = blockIdx.x;
  const int xcd = bid & 7, idx = bid >> 3;     // idx 0..191
  const int nt = idx % 24, mt = idx / 24;      // mt 0..7, nt 0..23
  const int m0 = (((xcd >> 1) << 3) + mt) * 128;
  const int n0 = (((xcd & 1) * 24) + nt) * 64;
  const int wm = w * 32;
  f32x4 acc[2][4] = {};

  const size_t ldb = (size_t)K * 2;
  // Staging: A = 512 chunks (128 rows x 4 slots), B = 256 chunks (64 x 4).
  // Source column pre-swizzled: cb' = slot*16 ^ (((row>>1)&3)<<4).
  const int ca0 = tid, ca1 = tid + 256, cb = tid;
  const int ra0 = ca0 >> 2, sa0 = ((ca0 & 3) * 16) ^ (((ra0 >> 1) & 3) << 4);
  const int ra1 = ca1 >> 2, sa1 = ((ca1 & 3) * 16) ^ (((ra1 >> 1) & 3) << 4);
  const int rb  = cb  >> 2, sb  = ((cb  & 3) * 16) ^ (((rb  >> 1) & 3) << 4);
  const char* A0 = (const char*)(A + (size_t)m0 * K) + (size_t)ra0 * ldb + sa0;
  const char* A1 = (const char*)(A + (size_t)m0 * K) + (size_t)ra1 * ldb + sa1;
  const char* B0 = (const char*)(B + (size_t)n0 * K) + (size_t)rb  * ldb + sb;

  auto stage = [&](int bo) {
    gl2lds16(A0, lds + bo + ca0 * 16);
    gl2lds16(A1, lds + bo + ca1 * 16);
    gl2lds16(B0, lds + bo + 8192 + cb * 16);
    A0 += 64; A1 += 64; B0 += 64;  // advance 32 k (64B)
  };

  stage(0);  // prologue: tile 0 into buffer 0 (3 loads/thread in flight)

  const int swz = ((lr >> 1) & 3) << 4;  // (row>>1)&3 == (lr>>1)&3
  const int NSTEP = K / 32;
  for (int kt = 0; kt < NSTEP; ++kt) {
    const int bo = (kt & 1) * 12288;
    if (kt + 1 < NSTEP) {
      stage(bo ^ 12288);
      asm volatile("s_waitcnt vmcnt(3)" ::: "memory");  // cur tile's 3 done
    } else {
      asm volatile("s_waitcnt vmcnt(0)" ::: "memory");
    }
    __builtin_amdgcn_s_barrier();

    bf16x8 af[2], bfr[4];
#pragma unroll
    for (int i = 0; i < 2; ++i)
      af[i] = *(const bf16x8*)(lds + bo + (wm + i * 16 + lr) * 64 + ((g * 16) ^ swz));
#pragma unroll
    for (int j = 0; j < 4; ++j)
      bfr[j] = *(const bf16x8*)(lds + bo + 8192 + (j * 16 + lr) * 64 + ((g * 16) ^ swz));
    __builtin_amdgcn_s_setprio(1);
#pragma unroll
    for (int i = 0; i < 2; ++i)
#pragma unroll
      for (int j = 0; j < 4; ++j)
        acc[i][j] = __builtin_amdgcn_mfma_f32_16x16x32_bf16(af[i], bfr[j], acc[i][j], 0, 0, 0);
    __builtin_amdgcn_s_setprio(0);
    asm volatile("s_waitcnt lgkmcnt(0)" ::: "memory");
    __builtin_amdgcn_s_barrier();  // cur buffer free for next stage
  }

  // ---- fused epilogue (n-tile = one 64-wide head slice) ----
  const int sel = n0 >> 10;  // 0 Q, 1 K, 2 V (uniform per block)
  if (sel <= 1) {
    const float qscale = (sel == 0) ? 0.125f * 1.44269504088896f : 1.0f;
    unsigned short* dst = (sel == 0) ? Qs : Ks;
#pragma unroll
    for (int j = 0; j < 4; ++j) {
      const int nn = (n0 + j * 16 + lr) & 1023;
      const int h = nn >> 6, d = nn & 63;
      const float2* tabrow = tab + (d >> 1);
      const float sgn = (d & 1) ? 1.0f : -1.0f;
#pragma unroll
      for (int i = 0; i < 2; ++i) {
#pragma unroll
        for (int r = 0; r < 4; ++r) {
          const int m = m0 + wm + i * 16 + g * 4 + r;
          const int l = m & 2047, b = m >> 11;
          float own = acc[i][j][r];
          float part = __shfl_xor(own, 1);
          float2 cs = tabrow[l * 32];
          float out = fmaf(cs.x, own, sgn * cs.y * part) * qscale;
          dst[((size_t)((b * 16 + h) * 2048 + l)) * 64 + d] = f2bf(out);
        }
      }
    }
  } else {
    // V: no rotation; scatter to Vt[bh][d][perm(l)] (column-permuted, so the
    // attention PV B-frag needs no cross-lane moves). perm(l0+r)=perm(l0)+r.
#pragma unroll
    for (int j = 0; j < 4; ++j) {
      const int nn = (n0 + j * 16 + lr) & 1023;
      const int h = nn >> 6, d = nn & 63;
#pragma unroll
      for (int i = 0; i < 2; ++i) {
        const int mb = m0 + wm + i * 16 + g * 4;
        const int l0 = mb & 2047, b = mb >> 11;
        const int pl = (l0 & ~31) + 8 * ((l0 & 15) >> 2) + 4 * ((l0 >> 4) & 1) + (l0 & 3);
        ushort4 v4;
        v4.x = f2bf(acc[i][j][0]); v4.y = f2bf(acc[i][j][1]);
        v4.z = f2bf(acc[i][j][2]); v4.w = f2bf(acc[i][j][3]);
        *(ushort4*)(Vt + ((size_t)((b * 16 + h) * 64 + d)) * 2048 + pl) = v4;
      }
    }
  }
}

// ---------------- GEMM2: 64x64 tile, f32 out, double-buffered ---------------
__global__ __launch_bounds__(256) void gemm2_64(
    const __hip_bfloat16* __restrict__ A,
    const __hip_bfloat16* __restrict__ B,
    float* __restrict__ C, int M, int N, int K) {
  __shared__ __align__(16) char lds[16384];  // [0,8K) As x2, [8K,16K) Bs x2
  const int tid = threadIdx.x, lane = tid & 63, w = tid >> 6;
  const int g = lane >> 4, lr = lane & 15;
  const int n0 = blockIdx.x * 64, m0 = blockIdx.y * 64;
  f32x4 acc[4] = {};

  const size_t ld = (size_t)K * 2;
  const int o16 = tid * 16;
  const int s = o16 ^ (((o16 >> 7) & 3) << 4);
  const int srow = s >> 6, scolb = s & 63;
  const char* Asrc = (const char*)(A + (size_t)m0 * K) + (size_t)srow * ld + scolb;
  const char* Bsrc = (const char*)(B + (size_t)n0 * K) + (size_t)srow * ld + scolb;

  auto stage = [&](int bo) {
    gl2lds16(Asrc, lds + bo + o16);
    gl2lds16(Bsrc, lds + 8192 + bo + o16);
    Asrc += 64; Bsrc += 64;
  };

  stage(0);  // prologue

  const int swz = ((lr >> 1) & 3) << 4;  // read-side swizzle
  const int NSTEP = K / 32;       // 32
  for (int kt = 0; kt < NSTEP; ++kt) {
    const int bo = (kt & 1) * 4096;
    if (kt + 1 < NSTEP) {
      stage(bo ^ 4096);
      asm volatile("s_waitcnt vmcnt(2)" ::: "memory");
    } else {
      asm volatile("s_waitcnt vmcnt(0)" ::: "memory");
    }
    __builtin_amdgcn_s_barrier();

    bf16x8 af = *(const bf16x8*)(lds + bo + (w * 16 + lr) * 64 + ((g * 16) ^ swz));
    __builtin_amdgcn_s_setprio(1);
#pragma unroll
    for (int j = 0; j < 4; ++j) {
      bf16x8 bf = *(const bf16x8*)(lds + 8192 + bo + (j * 16 + lr) * 64 + ((g * 16) ^ swz));
      acc[j] = __builtin_amdgcn_mfma_f32_16x16x32_bf16(af, bf, acc[j], 0, 0, 0);
    }
    __builtin_amdgcn_s_setprio(0);
    asm volatile("s_waitcnt lgkmcnt(0)" ::: "memory");
    __builtin_amdgcn_s_barrier();
  }

  // C/D layout: n = n0 + j*16 + lr, m = m0 + w*16 + g*4 + r.
#pragma unroll
  for (int j = 0; j < 4; ++j) {
    int n = n0 + j * 16 + lr;
#pragma unroll
    for (int r = 0; r < 4; ++r) {
      int m = m0 + w * 16 + g * 4 + r;
      C[(size_t)m * N + n] = acc[j][r];
    }
  }
}

// ---------------- Flash attention, split-K=2, P in registers ----------------
// (round-10 version, verbatim: 48.5us, MfmaUtil 31%, zero bank conflicts)
__global__ __launch_bounds__(256, 4) void attn_fwd(
    const __hip_bfloat16* __restrict__ Qs,
    const __hip_bfloat16* __restrict__ Ks,
    const __hip_bfloat16* __restrict__ Vt,
    float* __restrict__ Opart,
    float2* __restrict__ Ml) {
  constexpr int L = 2048;
  __shared__ __align__(16) char lds[32768];  // [0,16K) Kt x2, [16K,32K) Vt x2
  const int tid = threadIdx.x, lane = tid & 63, w = tid >> 6;
  const int g = lane >> 4, lr = lane & 15;
  const int blk = blockIdx.x;
  const int xcd = blk & 7, slot = blk >> 3;   // 128 slots per XCD
  const int bh = xcd * 4 + (slot >> 5);       // 4 bh per XCD
  const int rem = slot & 31;
  const int qt = rem >> 1, half = rem & 1;
  const int q0 = qt * 128 + w * 32 + lr;      // q-group 0 row; qg1 = q0+16
  const int kt0 = half * 16;

  const __hip_bfloat16* Qr = Qs + ((size_t)bh * L + q0) * 64;
  bf16x8 qf[2][2];
  qf[0][0] = *(const bf16x8*)(Qr + g * 8);
  qf[0][1] = *(const bf16x8*)(Qr + 32 + g * 8);
  qf[1][0] = *(const bf16x8*)(Qr + 16 * 64 + g * 8);
  qf[1][1] = *(const bf16x8*)(Qr + 16 * 64 + 32 + g * 8);

  bf16x8 onesf;
#pragma unroll
  for (int j = 0; j < 8; ++j) onesf[j] = (__bf16)1.0f;

  // LDS frag addressing (XOR-swizzled 128B rows):
  const int xmask = (lr & 7) << 4;
  const int loff0 = ((g * 16) ^ (xmask & 0x30)) + (xmask & 0x40);
  const int kb0 = lr * 128 + loff0;
  const int kb1 = kb0 ^ 64;

  // Staging: 2 K-chunks + 2 V-chunks (16B) per thread per tile.
  const int c0 = tid * 16, c1 = c0 + 4096;
  const int os0 = c0 ^ (((c0 >> 7) & 7) << 4);
  const int os1 = c1 ^ (((c1 >> 7) & 7) << 4);
  const char* Kb = (const char*)(Ks + (size_t)bh * L * 64) + (size_t)kt0 * 8192;
  const char* Vb = (const char*)(Vt + (size_t)bh * 64 * L) + kt0 * 128;
  const char* KsrcA = Kb + os0;
  const char* KsrcB = Kb + os1;
  const char* VsrcA = Vb + (size_t)(os0 >> 7) * (L * 2) + (os0 & 127);
  const char* VsrcB = Vb + (size_t)(os1 >> 7) * (L * 2) + (os1 & 127);

  auto stage = [&](int bo) {
    gl2lds16(KsrcA, lds + bo + c0);
    gl2lds16(KsrcB, lds + bo + c1);
    gl2lds16(VsrcA, lds + 16384 + bo + c0);
    gl2lds16(VsrcB, lds + 16384 + bo + c1);
    KsrcA += 8192; KsrcB += 8192; VsrcA += 128; VsrcB += 128;
  };

  f32x4 oacc[2][4] = {};
  f32x4 lacc[2] = {};
  float mrun[2] = {-1e30f, -1e30f};

  stage(0);  // prologue: 4 loads in flight

  for (int kt = 0; kt < 16; ++kt) {
    const int bo = (kt & 1) * 8192;
    if (kt + 1 < 16) {
      stage(bo ^ 8192);
      asm volatile("s_waitcnt vmcnt(4)" ::: "memory");  // cur tile's 4 done
    } else {
      asm volatile("s_waitcnt vmcnt(0)" ::: "memory");
    }
    __builtin_amdgcn_s_barrier();

    const char* Kc = lds + bo;
    const char* Vc = lds + 16384 + bo;

    // QK^T (swapped): sacc[qg][mf][r] = S^T[k=16mf+4g+r][q=lr], log2 units.
    f32x4 sacc[2][4] = {};
    __builtin_amdgcn_s_setprio(1);
#pragma unroll
    for (int mf = 0; mf < 4; ++mf) {
      bf16x8 a0 = *(const bf16x8*)(Kc + kb0 + mf * 2048);
      bf16x8 a1 = *(const bf16x8*)(Kc + kb1 + mf * 2048);
      sacc[0][mf] = __builtin_amdgcn_mfma_f32_16x16x32_bf16(a0, qf[0][0], sacc[0][mf], 0, 0, 0);
      sacc[0][mf] = __builtin_amdgcn_mfma_f32_16x16x32_bf16(a1, qf[0][1], sacc[0][mf], 0, 0, 0);
      sacc[1][mf] = __builtin_amdgcn_mfma_f32_16x16x32_bf16(a0, qf[1][0], sacc[1][mf], 0, 0, 0);
      sacc[1][mf] = __builtin_amdgcn_mfma_f32_16x16x32_bf16(a1, qf[1][1], sacc[1][mf], 0, 0, 0);
    }
    __builtin_amdgcn_s_setprio(0);

    // Softmax (log2 units). Per-lane local max (max3-shaped tree); full
    // cross-lane reduce + rescale only when some lane exceeds mrun+8.
#pragma unroll
    for (int qg = 0; qg < 2; ++qg) {
      float a0 = fmaxf(fmaxf(sacc[qg][0][0], sacc[qg][0][1]), sacc[qg][0][2]);
      float a1 = fmaxf(fmaxf(sacc[qg][0][3], sacc[qg][1][0]), sacc[qg][1][1]);
      float a2 = fmaxf(fmaxf(sacc[qg][1][2], sacc[qg][1][3]), sacc[qg][2][0]);
      float a3 = fmaxf(fmaxf(sacc[qg][2][1], sacc[qg][2][2]), sacc[qg][2][3]);
      float a4 = fmaxf(fmaxf(sacc[qg][3][0], sacc[qg][3][1]), sacc[qg][3][2]);
      float b0 = fmaxf(fmaxf(a0, a1), a2);
      float b1 = fmaxf(fmaxf(a3, a4), sacc[qg][3][3]);
      float lmax = fmaxf(b0, b1);
      if (__any(lmax > mrun[qg] + 8.0f)) {
        float tmax = fmaxf(lmax, __shfl_xor(lmax, 16));
        tmax = fmaxf(tmax, __shfl_xor(tmax, 32));
        float mnew = fmaxf(mrun[qg], tmax);
        float al = __builtin_amdgcn_exp2f(mrun[qg] - mnew);
        mrun[qg] = mnew;
        lacc[qg] *= al;
#pragma unroll
        for (int d = 0; d < 4; ++d) oacc[qg][d] = oacc[qg][d] * al;
      }
#pragma unroll
      for (int mf = 0; mf < 4; ++mf) {
        sacc[qg][mf][0] = __builtin_amdgcn_exp2f(sacc[qg][mf][0] - mrun[qg]);
        sacc[qg][mf][1] = __builtin_amdgcn_exp2f(sacc[qg][mf][1] - mrun[qg]);
        sacc[qg][mf][2] = __builtin_amdgcn_exp2f(sacc[qg][mf][2] - mrun[qg]);
        sacc[qg][mf][3] = __builtin_amdgcn_exp2f(sacc[qg][mf][3] - mrun[qg]);
      }
    }

    // PV: O^T = mfma(A=V-frag, B=P-frag). Vt's permuted k-layout means the
    // B-frag for slice ks is just {p[2ks][0..3], p[2ks+1][0..3]} in-lane.
    // lacc = mfma(ones, pf): every lane accumulates its q-row's sum(P).
#pragma unroll
    for (int ks = 0; ks < 2; ++ks) {
      bf16x8 pf[2];
#pragma unroll
      for (int qg = 0; qg < 2; ++qg) {
#pragma unroll
        for (int j = 0; j < 4; ++j) {
          pf[qg][j]     = (__bf16)sacc[qg][2 * ks][j];
          pf[qg][4 + j] = (__bf16)sacc[qg][2 * ks + 1][j];
        }
      }
      const int kb = ks ? kb1 : kb0;
      __builtin_amdgcn_s_setprio(1);
      lacc[0] = __builtin_amdgcn_mfma_f32_16x16x32_bf16(onesf, pf[0], lacc[0], 0, 0, 0);
      lacc[1] = __builtin_amdgcn_mfma_f32_16x16x32_bf16(onesf, pf[1], lacc[1], 0, 0, 0);
#pragma unroll
      for (int df = 0; df < 4; ++df) {
        bf16x8 a = *(const bf16x8*)(Vc + kb + df * 2048);
        oacc[0][df] = __builtin_amdgcn_mfma_f32_16x16x32_bf16(a, pf[0], oacc[0][df], 0, 0, 0);
        oacc[1][df] = __builtin_amdgcn_mfma_f32_16x16x32_bf16(a, pf[1], oacc[1][df], 0, 0, 0);
      }
      __builtin_amdgcn_s_setprio(0);
    }
    asm volatile("s_waitcnt lgkmcnt(0)" ::: "memory");
    __builtin_amdgcn_s_barrier();  // cur buffers free for next stage
  }

#pragma unroll
  for (int qg = 0; qg < 2; ++qg) {
    const size_t rowi = ((size_t)bh * L + q0 + qg * 16) * 2 + half;
    float* Od = Opart + rowi * 64;
#pragma unroll
    for (int df = 0; df < 4; ++df)
      *(f32x4*)(Od + df * 16 + g * 4) = oacc[qg][df];
    if (g == 0) {
      float2 ml; ml.x = mrun[qg]; ml.y = lacc[qg][0];
      Ml[rowi] = ml;
    }
  }
}

// ---------------- Split-K combine: Ob[b][l][h*64+d] = sum(Opart)/l ----------
__global__ __launch_bounds__(256) void attn_reduce(
    const float* __restrict__ Opart, const float2* __restrict__ Ml,
    unsigned short* __restrict__ Ob) {
  int t = blockIdx.x * 256 + threadIdx.x;
  int d = t & 63;
  int r = t >> 6;  // 0..65535 = bh*2048 + q
  float2 a = Ml[2 * r], b = Ml[2 * r + 1];
  float m = fmaxf(a.x, b.x);
  float w0 = __builtin_amdgcn_exp2f(a.x - m);
  float w1 = __builtin_amdgcn_exp2f(b.x - m);
  float l = a.y * w0 + b.y * w1;
  float o = Opart[(size_t)(2 * r) * 64 + d] * w0 + Opart[(size_t)(2 * r + 1) * 64 + d] * w1;
  float out = o / l;
  int bh = r >> 11, qq = r & 2047;
  Ob[(((size_t)(bh >> 4) * 2048 + qq)) * 1024 + (bh & 15) * 64 + d] = f2bf(out);
}

// ---------------- launch ----------------
extern "C" void kernel_launch(void* const* d_in, const int* in_sizes, int n_in,
                              void* d_out, int out_size, void* d_ws, size_t ws_size,
                              hipStream_t stream) {
  (void)in_sizes; (void)n_in; (void)out_size; (void)ws_size;
  const float* x    = (const float*)d_in[0];   // [2,2048,1024]
  const float* wqkv = (const float*)d_in[1];   // [3072,1024]
  const float* wout = (const float*)d_in[2];   // [1024,1024]

  char* ws = (char*)d_ws;
  // Workspace (66MB):
  //  [0..2M)   wob          (alive until gemm2)
  //  [2..10M)  Qsb, later Ob (Qsb dead after attn; Ob written by reduce)
  //  [10..18M) Ksb
  //  [18..26M) Vtb
  //  [26..58M) Opart (f32, 32MiB)
  //  [50..58M) xb           (dead before attn writes Opart tail - OK)
  //  [58..59M) Ml
  //  [59..59.5M) RoPE cos/sin table (float2 [2048][32])
  //  [59.5..65.5M) wqb (6MB)
  auto* wob   = (__hip_bfloat16*)(ws + ((size_t)0u  << 20));
  auto* Qsb   = (__hip_bfloat16*)(ws + ((size_t)2u  << 20));
  auto* Ob    = (__hip_bfloat16*)(ws + ((size_t)2u  << 20));
  auto* Ksb   = (__hip_bfloat16*)(ws + ((size_t)10u << 20));
  auto* Vtb   = (__hip_bfloat16*)(ws + ((size_t)18u << 20));
  auto* Opart = (float*)         (ws + ((size_t)26u << 20));
  auto* xb    = (__hip_bfloat16*)(ws + ((size_t)50u << 20));
  auto* Mlp   = (float2*)        (ws + ((size_t)58u << 20));
  auto* tab   = (float2*)        (ws + ((size_t)59u << 20));
  auto* wqb   = (__hip_bfloat16*)(ws + (((size_t)59u << 20) + ((size_t)1u << 19)));

  cvt_all<<<8448, 256, 0, stream>>>((const float4*)x, (const float4*)wqkv,
                                    (const float4*)wout,
                                    (ushort4*)xb, (ushort4*)wqb, (ushort4*)wob,
                                    tab);
  gemm1_fused<<<1536, 256, 0, stream>>>(xb, wqb,
                                        (unsigned short*)Qsb,
                                        (unsigned short*)Ksb,
                                        (unsigned short*)Vtb,
                                        tab, 1024);
  attn_fwd<<<1024, 256, 0, stream>>>(Qsb, Ksb, Vtb, Opart, Mlp);
  attn_reduce<<<16384, 256, 0, stream>>>(Opart, Mlp, (unsigned short*)Ob);
  gemm2_64<<<dim3(16, 64), 256, 0, stream>>>(Ob, wob, (float*)d_out,
                                             4096, 1024, 1024);
}

// Round 16
// 131.491 us; speedup vs baseline: 1.0453x; 1.0453x over previous
//
#include <hip/hip_runtime.h>
#include <hip/hip_bf16.h>
#include <stdint.h>

// Problem constants: B=2, L=2048, D=1024, H=16, hd=64, scale=1/8 (log2e-folded).

typedef __bf16 bf16x8 __attribute__((ext_vector_type(8)));
typedef float f32x4 __attribute__((ext_vector_type(4)));

__device__ __forceinline__ unsigned short f2bf(float f) {
  union { float f; unsigned int u; } v; v.f = f;
  unsigned int r = v.u + 0x7FFFu + ((v.u >> 16) & 1u);  // RNE
  return (unsigned short)(r >> 16);
}
__device__ __forceinline__ float b2f(unsigned short u) {
  union { unsigned int u; float f; } v; v.u = ((unsigned int)u) << 16;
  return v.f;
}

__device__ __forceinline__ void gl2lds16(const void* gptr, void* lptr) {
  __builtin_amdgcn_global_load_lds(
      (const __attribute__((address_space(1))) unsigned int*)gptr,
      (__attribute__((address_space(3))) unsigned int*)lptr, 16, 0, 0);
}

// ------- fp32 -> bf16 conversion (x | W_qkv | W_out) + RoPE cos/sin table ---
__global__ void cvt_all(const float4* __restrict__ x,
                        const float4* __restrict__ wq,
                        const float4* __restrict__ wo,
                        ushort4* __restrict__ xb,
                        ushort4* __restrict__ wqb,
                        ushort4* __restrict__ wob,
                        float2* __restrict__ tab) {
  int i = blockIdx.x * 256 + threadIdx.x;
  if (i >= 2097152) {
    int t = i - 2097152;         // 0..65535 = l*32 + fi
    int l = t >> 5, fi = t & 31;
    float inv_freq = powf(10000.0f, -(float)fi / 32.0f);
    float s, c;
    sincosf((float)l * inv_freq, &s, &c);
    tab[t] = make_float2(c, s);
    return;
  }
  float4 v; ushort4* dst; int j;
  if (i < 1048576)      { v = x[i];            dst = xb;  j = i; }
  else if (i < 1835008) { v = wq[i - 1048576]; dst = wqb; j = i - 1048576; }
  else                  { v = wo[i - 1835008]; dst = wob; j = i - 1835008; }
  ushort4 o;
  o.x = f2bf(v.x); o.y = f2bf(v.y); o.z = f2bf(v.z); o.w = f2bf(v.w);
  dst[j] = o;
}

// ---------------- GEMM1 + fused RoPE/scatter epilogue -----------------------
// 128x128 tile, BK=32. TRIPLE-buffered staging (depth-2 prefetch): loads for
// tile t are issued at iter t-2, ~2 iterations (>1100 cyc) before the
// counted vmcnt(8) wait -- covers the ~900cyc HBM latency that the dbuf
// version stalled on every iter (r15 analysis: ideal ~7us/CU vs 57us seen).
// Buffer safety: buf (t+2)%3 was last read at iter t-1; the end-of-compute
// barrier protects it (same invariant as dbuf). Conflict-free swizzle (r14).
__global__ __launch_bounds__(256) void gemm1_fused(
    const __hip_bfloat16* __restrict__ A,
    const __hip_bfloat16* __restrict__ B,
    unsigned short* __restrict__ Qs,
    unsigned short* __restrict__ Ks,
    unsigned short* __restrict__ Vt,
    const float2* __restrict__ tab, int K) {
  __shared__ __align__(16) char lds[49152];  // 3 bufs x (8K A + 8K B)
  const int tid = threadIdx.x;
  const int lane = tid & 63;
  const int wave = tid >> 6;
  const int wm = (wave >> 1) * 64, wn = (wave & 1) * 64;
  const int g = lane >> 4, lr = lane & 15;
  const int m0 = blockIdx.y * 128, n0 = blockIdx.x * 128;
  f32x4 acc[4][4] = {};

  const size_t ldb = (size_t)K * 2;
  const int c0 = tid, c1 = tid + 256;
  const int r0 = c0 >> 2, cb0 = ((c0 & 3) * 16) ^ (((r0 >> 1) & 3) << 4);
  const int r1 = c1 >> 2, cb1 = ((c1 & 3) * 16) ^ (((r1 >> 1) & 3) << 4);
  const char* A0 = (const char*)(A + (size_t)m0 * K) + (size_t)r0 * ldb + cb0;
  const char* A1 = (const char*)(A + (size_t)m0 * K) + (size_t)r1 * ldb + cb1;
  const char* B0 = (const char*)(B + (size_t)n0 * K) + (size_t)r0 * ldb + cb0;
  const char* B1 = (const char*)(B + (size_t)n0 * K) + (size_t)r1 * ldb + cb1;

  auto stage = [&](int bo) {
    gl2lds16(A0, lds + bo + c0 * 16);
    gl2lds16(A1, lds + bo + c1 * 16);
    gl2lds16(B0, lds + bo + 8192 + c0 * 16);
    gl2lds16(B1, lds + bo + 8192 + c1 * 16);
    A0 += 64; A1 += 64; B0 += 64; B1 += 64;  // advance 32 k (64B)
  };

  stage(0);      // tile 0 -> buf 0
  stage(16384);  // tile 1 -> buf 1   (8 loads in flight)

  const int swz = ((lr >> 1) & 3) << 4;  // (row>>1)&3 == (lr>>1)&3
  const int NSTEP = K / 32;
  for (int kt = 0; kt < NSTEP; ++kt) {
    const int bo = (kt % 3) * 16384;
    if (kt + 2 < NSTEP) {
      stage(((kt + 2) % 3) * 16384);
      asm volatile("s_waitcnt vmcnt(8)" ::: "memory");  // tile kt's 4 done
    } else if (kt + 1 < NSTEP) {
      asm volatile("s_waitcnt vmcnt(4)" ::: "memory");
    } else {
      asm volatile("s_waitcnt vmcnt(0)" ::: "memory");
    }
    __builtin_amdgcn_s_barrier();

    bf16x8 af[4], bfr[4];
#pragma unroll
    for (int i = 0; i < 4; ++i)
      af[i] = *(const bf16x8*)(lds + bo + (wm + i * 16 + lr) * 64 + ((g * 16) ^ swz));
#pragma unroll
    for (int i = 0; i < 4; ++i)
      bfr[i] = *(const bf16x8*)(lds + bo + 8192 + (wn + i * 16 + lr) * 64 + ((g * 16) ^ swz));
    __builtin_amdgcn_s_setprio(1);
#pragma unroll
    for (int i = 0; i < 4; ++i)
#pragma unroll
      for (int j = 0; j < 4; ++j)
        acc[i][j] = __builtin_amdgcn_mfma_f32_16x16x32_bf16(af[i], bfr[j], acc[i][j], 0, 0, 0);
    __builtin_amdgcn_s_setprio(0);
    asm volatile("s_waitcnt lgkmcnt(0)" ::: "memory");
    __builtin_amdgcn_s_barrier();  // reads done before this buf is re-staged
  }

  // ---- fused epilogue ----
  const int sel = n0 >> 10;  // 0 Q, 1 K, 2 V (uniform per block)
  if (sel <= 1) {
    const float qscale = (sel == 0) ? 0.125f * 1.44269504088896f : 1.0f;
    unsigned short* dst = (sel == 0) ? Qs : Ks;
#pragma unroll
    for (int j = 0; j < 4; ++j) {
      const int nn = (n0 + wn + j * 16 + lr) & 1023;
      const int h = nn >> 6, d = nn & 63;
      const float2* tabrow = tab + (d >> 1);
      const float sgn = (d & 1) ? 1.0f : -1.0f;
#pragma unroll
      for (int i = 0; i < 4; ++i) {
#pragma unroll
        for (int r = 0; r < 4; ++r) {
          const int m = m0 + wm + i * 16 + g * 4 + r;
          const int l = m & 2047, b = m >> 11;
          float own = acc[i][j][r];
          float part = __shfl_xor(own, 1);
          float2 cs = tabrow[l * 32];
          float out = fmaf(cs.x, own, sgn * cs.y * part) * qscale;
          dst[((size_t)((b * 16 + h) * 2048 + l)) * 64 + d] = f2bf(out);
        }
      }
    }
  } else {
    // V: no rotation; scatter to Vt[bh][d][perm(l)] (column-permuted, so the
    // attention PV B-frag needs no cross-lane moves). perm(l0+r)=perm(l0)+r.
#pragma unroll
    for (int j = 0; j < 4; ++j) {
      const int nn = (n0 + wn + j * 16 + lr) & 1023;
      const int h = nn >> 6, d = nn & 63;
#pragma unroll
      for (int i = 0; i < 4; ++i) {
        const int mb = m0 + wm + i * 16 + g * 4;
        const int l0 = mb & 2047, b = mb >> 11;
        const int pl = (l0 & ~31) + 8 * ((l0 & 15) >> 2) + 4 * ((l0 >> 4) & 1) + (l0 & 3);
        ushort4 v4;
        v4.x = f2bf(acc[i][j][0]); v4.y = f2bf(acc[i][j][1]);
        v4.z = f2bf(acc[i][j][2]); v4.w = f2bf(acc[i][j][3]);
        *(ushort4*)(Vt + ((size_t)((b * 16 + h) * 64 + d)) * 2048 + pl) = v4;
      }
    }
  }
}

// ---------------- GEMM2: 64x64 tile, f32 out, TRIPLE-buffered ---------------
// Same depth-2 prefetch; 3 bufs x (4K A + 4K B) = 24KB -> 6 blocks/CU.
__global__ __launch_bounds__(256) void gemm2_64(
    const __hip_bfloat16* __restrict__ A,
    const __hip_bfloat16* __restrict__ B,
    float* __restrict__ C, int M, int N, int K) {
  __shared__ __align__(16) char lds[24576];  // A: buf*4096, B: 12288+buf*4096
  const int tid = threadIdx.x, lane = tid & 63, w = tid >> 6;
  const int g = lane >> 4, lr = lane & 15;
  const int n0 = blockIdx.x * 64, m0 = blockIdx.y * 64;
  f32x4 acc[4] = {};

  const size_t ld = (size_t)K * 2;
  const int o16 = tid * 16;
  const int s = o16 ^ (((o16 >> 7) & 3) << 4);
  const int srow = s >> 6, scolb = s & 63;
  const char* Asrc = (const char*)(A + (size_t)m0 * K) + (size_t)srow * ld + scolb;
  const char* Bsrc = (const char*)(B + (size_t)n0 * K) + (size_t)srow * ld + scolb;

  auto stage = [&](int buf) {
    gl2lds16(Asrc, lds + buf * 4096 + o16);
    gl2lds16(Bsrc, lds + 12288 + buf * 4096 + o16);
    Asrc += 64; Bsrc += 64;
  };

  stage(0);  // tile 0
  stage(1);  // tile 1  (4 loads in flight)

  const int swz = ((lr >> 1) & 3) << 4;  // read-side swizzle
  const int NSTEP = K / 32;       // 32
  for (int kt = 0; kt < NSTEP; ++kt) {
    const int buf = kt % 3;
    if (kt + 2 < NSTEP) {
      stage((kt + 2) % 3);
      asm volatile("s_waitcnt vmcnt(4)" ::: "memory");  // tile kt's 2 done
    } else if (kt + 1 < NSTEP) {
      asm volatile("s_waitcnt vmcnt(2)" ::: "memory");
    } else {
      asm volatile("s_waitcnt vmcnt(0)" ::: "memory");
    }
    __builtin_amdgcn_s_barrier();

    bf16x8 af = *(const bf16x8*)(lds + buf * 4096 + (w * 16 + lr) * 64 + ((g * 16) ^ swz));
    __builtin_amdgcn_s_setprio(1);
#pragma unroll
    for (int j = 0; j < 4; ++j) {
      bf16x8 bf = *(const bf16x8*)(lds + 12288 + buf * 4096 + (j * 16 + lr) * 64 + ((g * 16) ^ swz));
      acc[j] = __builtin_amdgcn_mfma_f32_16x16x32_bf16(af, bf, acc[j], 0, 0, 0);
    }
    __builtin_amdgcn_s_setprio(0);
    asm volatile("s_waitcnt lgkmcnt(0)" ::: "memory");
    __builtin_amdgcn_s_barrier();
  }

  // C/D layout: n = n0 + j*16 + lr, m = m0 + w*16 + g*4 + r.
#pragma unroll
  for (int j = 0; j < 4; ++j) {
    int n = n0 + j * 16 + lr;
#pragma unroll
    for (int r = 0; r < 4; ++r) {
      int m = m0 + w * 16 + g * 4 + r;
      C[(size_t)m * N + n] = acc[j][r];
    }
  }
}

// ---------------- Flash attention, split-K=2, P in registers ----------------
// (round-10 version, verbatim: 48.5us, MfmaUtil 31%, zero bank conflicts)
__global__ __launch_bounds__(256, 4) void attn_fwd(
    const __hip_bfloat16* __restrict__ Qs,
    const __hip_bfloat16* __restrict__ Ks,
    const __hip_bfloat16* __restrict__ Vt,
    float* __restrict__ Opart,
    float2* __restrict__ Ml) {
  constexpr int L = 2048;
  __shared__ __align__(16) char lds[32768];  // [0,16K) Kt x2, [16K,32K) Vt x2
  const int tid = threadIdx.x, lane = tid & 63, w = tid >> 6;
  const int g = lane >> 4, lr = lane & 15;
  const int blk = blockIdx.x;
  const int xcd = blk & 7, slot = blk >> 3;   // 128 slots per XCD
  const int bh = xcd * 4 + (slot >> 5);       // 4 bh per XCD
  const int rem = slot & 31;
  const int qt = rem >> 1, half = rem & 1;
  const int q0 = qt * 128 + w * 32 + lr;      // q-group 0 row; qg1 = q0+16
  const int kt0 = half * 16;

  const __hip_bfloat16* Qr = Qs + ((size_t)bh * L + q0) * 64;
  bf16x8 qf[2][2];
  qf[0][0] = *(const bf16x8*)(Qr + g * 8);
  qf[0][1] = *(const bf16x8*)(Qr + 32 + g * 8);
  qf[1][0] = *(const bf16x8*)(Qr + 16 * 64 + g * 8);
  qf[1][1] = *(const bf16x8*)(Qr + 16 * 64 + 32 + g * 8);

  bf16x8 onesf;
#pragma unroll
  for (int j = 0; j < 8; ++j) onesf[j] = (__bf16)1.0f;

  // LDS frag addressing (XOR-swizzled 128B rows):
  const int xmask = (lr & 7) << 4;
  const int loff0 = ((g * 16) ^ (xmask & 0x30)) + (xmask & 0x40);
  const int kb0 = lr * 128 + loff0;
  const int kb1 = kb0 ^ 64;

  // Staging: 2 K-chunks + 2 V-chunks (16B) per thread per tile.
  const int c0 = tid * 16, c1 = c0 + 4096;
  const int os0 = c0 ^ (((c0 >> 7) & 7) << 4);
  const int os1 = c1 ^ (((c1 >> 7) & 7) << 4);
  const char* Kb = (const char*)(Ks + (size_t)bh * L * 64) + (size_t)kt0 * 8192;
  const char* Vb = (const char*)(Vt + (size_t)bh * 64 * L) + kt0 * 128;
  const char* KsrcA = Kb + os0;
  const char* KsrcB = Kb + os1;
  const char* VsrcA = Vb + (size_t)(os0 >> 7) * (L * 2) + (os0 & 127);
  const char* VsrcB = Vb + (size_t)(os1 >> 7) * (L * 2) + (os1 & 127);

  auto stage = [&](int bo) {
    gl2lds16(KsrcA, lds + bo + c0);
    gl2lds16(KsrcB, lds + bo + c1);
    gl2lds16(VsrcA, lds + 16384 + bo + c0);
    gl2lds16(VsrcB, lds + 16384 + bo + c1);
    KsrcA += 8192; KsrcB += 8192; VsrcA += 128; VsrcB += 128;
  };

  f32x4 oacc[2][4] = {};
  f32x4 lacc[2] = {};
  float mrun[2] = {-1e30f, -1e30f};

  stage(0);  // prologue: 4 loads in flight

  for (int kt = 0; kt < 16; ++kt) {
    const int bo = (kt & 1) * 8192;
    if (kt + 1 < 16) {
      stage(bo ^ 8192);
      asm volatile("s_waitcnt vmcnt(4)" ::: "memory");  // cur tile's 4 done
    } else {
      asm volatile("s_waitcnt vmcnt(0)" ::: "memory");
    }
    __builtin_amdgcn_s_barrier();

    const char* Kc = lds + bo;
    const char* Vc = lds + 16384 + bo;

    // QK^T (swapped): sacc[qg][mf][r] = S^T[k=16mf+4g+r][q=lr], log2 units.
    f32x4 sacc[2][4] = {};
    __builtin_amdgcn_s_setprio(1);
#pragma unroll
    for (int mf = 0; mf < 4; ++mf) {
      bf16x8 a0 = *(const bf16x8*)(Kc + kb0 + mf * 2048);
      bf16x8 a1 = *(const bf16x8*)(Kc + kb1 + mf * 2048);
      sacc[0][mf] = __builtin_amdgcn_mfma_f32_16x16x32_bf16(a0, qf[0][0], sacc[0][mf], 0, 0, 0);
      sacc[0][mf] = __builtin_amdgcn_mfma_f32_16x16x32_bf16(a1, qf[0][1], sacc[0][mf], 0, 0, 0);
      sacc[1][mf] = __builtin_amdgcn_mfma_f32_16x16x32_bf16(a0, qf[1][0], sacc[1][mf], 0, 0, 0);
      sacc[1][mf] = __builtin_amdgcn_mfma_f32_16x16x32_bf16(a1, qf[1][1], sacc[1][mf], 0, 0, 0);
    }
    __builtin_amdgcn_s_setprio(0);

    // Softmax (log2 units). Per-lane local max (max3-shaped tree); full
    // cross-lane reduce + rescale only when some lane exceeds mrun+8.
#pragma unroll
    for (int qg = 0; qg < 2; ++qg) {
      float a0 = fmaxf(fmaxf(sacc[qg][0][0], sacc[qg][0][1]), sacc[qg][0][2]);
      float a1 = fmaxf(fmaxf(sacc[qg][0][3], sacc[qg][1][0]), sacc[qg][1][1]);
      float a2 = fmaxf(fmaxf(sacc[qg][1][2], sacc[qg][1][3]), sacc[qg][2][0]);
      float a3 = fmaxf(fmaxf(sacc[qg][2][1], sacc[qg][2][2]), sacc[qg][2][3]);
      float a4 = fmaxf(fmaxf(sacc[qg][3][0], sacc[qg][3][1]), sacc[qg][3][2]);
      float b0 = fmaxf(fmaxf(a0, a1), a2);
      float b1 = fmaxf(fmaxf(a3, a4), sacc[qg][3][3]);
      float lmax = fmaxf(b0, b1);
      if (__any(lmax > mrun[qg] + 8.0f)) {
        float tmax = fmaxf(lmax, __shfl_xor(lmax, 16));
        tmax = fmaxf(tmax, __shfl_xor(tmax, 32));
        float mnew = fmaxf(mrun[qg], tmax);
        float al = __builtin_amdgcn_exp2f(mrun[qg] - mnew);
        mrun[qg] = mnew;
        lacc[qg] *= al;
#pragma unroll
        for (int d = 0; d < 4; ++d) oacc[qg][d] = oacc[qg][d] * al;
      }
#pragma unroll
      for (int mf = 0; mf < 4; ++mf) {
        sacc[qg][mf][0] = __builtin_amdgcn_exp2f(sacc[qg][mf][0] - mrun[qg]);
        sacc[qg][mf][1] = __builtin_amdgcn_exp2f(sacc[qg][mf][1] - mrun[qg]);
        sacc[qg][mf][2] = __builtin_amdgcn_exp2f(sacc[qg][mf][2] - mrun[qg]);
        sacc[qg][mf][3] = __builtin_amdgcn_exp2f(sacc[qg][mf][3] - mrun[qg]);
      }
    }

    // PV: O^T = mfma(A=V-frag, B=P-frag). Vt's permuted k-layout means the
    // B-frag for slice ks is just {p[2ks][0..3], p[2ks+1][0..3]} in-lane.
    // lacc = mfma(ones, pf): every lane accumulates its q-row's sum(P).
#pragma unroll
    for (int ks = 0; ks < 2; ++ks) {
      bf16x8 pf[2];
#pragma unroll
      for (int qg = 0; qg < 2; ++qg) {
#pragma unroll
        for (int j = 0; j < 4; ++j) {
          pf[qg][j]     = (__bf16)sacc[qg][2 * ks][j];
          pf[qg][4 + j] = (__bf16)sacc[qg][2 * ks + 1][j];
        }
      }
      const int kb = ks ? kb1 : kb0;
      __builtin_amdgcn_s_setprio(1);
      lacc[0] = __builtin_amdgcn_mfma_f32_16x16x32_bf16(onesf, pf[0], lacc[0], 0, 0, 0);
      lacc[1] = __builtin_amdgcn_mfma_f32_16x16x32_bf16(onesf, pf[1], lacc[1], 0, 0, 0);
#pragma unroll
      for (int df = 0; df < 4; ++df) {
        bf16x8 a = *(const bf16x8*)(Vc + kb + df * 2048);
        oacc[0][df] = __builtin_amdgcn_mfma_f32_16x16x32_bf16(a, pf[0], oacc[0][df], 0, 0, 0);
        oacc[1][df] = __builtin_amdgcn_mfma_f32_16x16x32_bf16(a, pf[1], oacc[1][df], 0, 0, 0);
      }
      __builtin_amdgcn_s_setprio(0);
    }
    asm volatile("s_waitcnt lgkmcnt(0)" ::: "memory");
    __builtin_amdgcn_s_barrier();  // cur buffers free for next stage
  }

#pragma unroll
  for (int qg = 0; qg < 2; ++qg) {
    const size_t rowi = ((size_t)bh * L + q0 + qg * 16) * 2 + half;
    float* Od = Opart + rowi * 64;
#pragma unroll
    for (int df = 0; df < 4; ++df)
      *(f32x4*)(Od + df * 16 + g * 4) = oacc[qg][df];
    if (g == 0) {
      float2 ml; ml.x = mrun[qg]; ml.y = lacc[qg][0];
      Ml[rowi] = ml;
    }
  }
}

// ---------------- Split-K combine: Ob[b][l][h*64+d] = sum(Opart)/l ----------
__global__ __launch_bounds__(256) void attn_reduce(
    const float* __restrict__ Opart, const float2* __restrict__ Ml,
    unsigned short* __restrict__ Ob) {
  int t = blockIdx.x * 256 + threadIdx.x;
  int d = t & 63;
  int r = t >> 6;  // 0..65535 = bh*2048 + q
  float2 a = Ml[2 * r], b = Ml[2 * r + 1];
  float m = fmaxf(a.x, b.x);
  float w0 = __builtin_amdgcn_exp2f(a.x - m);
  float w1 = __builtin_amdgcn_exp2f(b.x - m);
  float l = a.y * w0 + b.y * w1;
  float o = Opart[(size_t)(2 * r) * 64 + d] * w0 + Opart[(size_t)(2 * r + 1) * 64 + d] * w1;
  float out = o / l;
  int bh = r >> 11, qq = r & 2047;
  Ob[(((size_t)(bh >> 4) * 2048 + qq)) * 1024 + (bh & 15) * 64 + d] = f2bf(out);
}

// ---------------- launch ----------------
extern "C" void kernel_launch(void* const* d_in, const int* in_sizes, int n_in,
                              void* d_out, int out_size, void* d_ws, size_t ws_size,
                              hipStream_t stream) {
  (void)in_sizes; (void)n_in; (void)out_size; (void)ws_size;
  const float* x    = (const float*)d_in[0];   // [2,2048,1024]
  const float* wqkv = (const float*)d_in[1];   // [3072,1024]
  const float* wout = (const float*)d_in[2];   // [1024,1024]

  char* ws = (char*)d_ws;
  // Workspace (66MB):
  //  [0..2M)   wob, [2..10M) Qsb/Ob, [10..18M) Ksb, [18..26M) Vtb,
  //  [26..58M) Opart, [50..58M) xb (dead before Opart tail written),
  //  [58..59M) Ml, [59..59.5M) RoPE table, [59.5..65.5M) wqb
  auto* wob   = (__hip_bfloat16*)(ws + ((size_t)0u  << 20));
  auto* Qsb   = (__hip_bfloat16*)(ws + ((size_t)2u  << 20));
  auto* Ob    = (__hip_bfloat16*)(ws + ((size_t)2u  << 20));
  auto* Ksb   = (__hip_bfloat16*)(ws + ((size_t)10u << 20));
  auto* Vtb   = (__hip_bfloat16*)(ws + ((size_t)18u << 20));
  auto* Opart = (float*)         (ws + ((size_t)26u << 20));
  auto* xb    = (__hip_bfloat16*)(ws + ((size_t)50u << 20));
  auto* Mlp   = (float2*)        (ws + ((size_t)58u << 20));
  auto* tab   = (float2*)        (ws + ((size_t)59u << 20));
  auto* wqb   = (__hip_bfloat16*)(ws + (((size_t)59u << 20) + ((size_t)1u << 19)));

  cvt_all<<<8448, 256, 0, stream>>>((const float4*)x, (const float4*)wqkv,
                                    (const float4*)wout,
                                    (ushort4*)xb, (ushort4*)wqb, (ushort4*)wob,
                                    tab);
  gemm1_fused<<<dim3(24, 32), 256, 0, stream>>>(xb, wqb,
                                                (unsigned short*)Qsb,
                                                (unsigned short*)Ksb,
                                                (unsigned short*)Vtb,
                                                tab, 1024);
  attn_fwd<<<1024, 256, 0, stream>>>(Qsb, Ksb, Vtb, Opart, Mlp);
  attn_reduce<<<16384, 256, 0, stream>>>(Opart, Mlp, (unsigned short*)Ob);
  gemm2_64<<<dim3(16, 64), 256, 0, stream>>>(Ob, wob, (float*)d_out,
                                             4096, 1024, 1024);
}

// Round 17
// 130.903 us; speedup vs baseline: 1.0499x; 1.0045x over previous
//
#include <hip/hip_runtime.h>
#include <hip/hip_bf16.h>
#include <stdint.h>

// Problem constants: B=2, L=2048, D=1024, H=16, hd=64, scale=1/8 (log2e-folded).

typedef __bf16 bf16x8 __attribute__((ext_vector_type(8)));
typedef float f32x4 __attribute__((ext_vector_type(4)));

__device__ __forceinline__ unsigned short f2bf(float f) {
  union { float f; unsigned int u; } v; v.f = f;
  unsigned int r = v.u + 0x7FFFu + ((v.u >> 16) & 1u);  // RNE
  return (unsigned short)(r >> 16);
}
__device__ __forceinline__ float b2f(unsigned short u) {
  union { unsigned int u; float f; } v; v.u = ((unsigned int)u) << 16;
  return v.f;
}

__device__ __forceinline__ void gl2lds16(const void* gptr, void* lptr) {
  __builtin_amdgcn_global_load_lds(
      (const __attribute__((address_space(1))) unsigned int*)gptr,
      (__attribute__((address_space(3))) unsigned int*)lptr, 16, 0, 0);
}

// ------- fp32 -> bf16 conversion (x | W_qkv | W_out) + RoPE cos/sin table ---
__global__ void cvt_all(const float4* __restrict__ x,
                        const float4* __restrict__ wq,
                        const float4* __restrict__ wo,
                        ushort4* __restrict__ xb,
                        ushort4* __restrict__ wqb,
                        ushort4* __restrict__ wob,
                        float2* __restrict__ tab) {
  int i = blockIdx.x * 256 + threadIdx.x;
  if (i >= 2097152) {
    int t = i - 2097152;         // 0..65535 = l*32 + fi
    int l = t >> 5, fi = t & 31;
    float inv_freq = powf(10000.0f, -(float)fi / 32.0f);
    float s, c;
    sincosf((float)l * inv_freq, &s, &c);
    tab[t] = make_float2(c, s);
    return;
  }
  float4 v; ushort4* dst; int j;
  if (i < 1048576)      { v = x[i];            dst = xb;  j = i; }
  else if (i < 1835008) { v = wq[i - 1048576]; dst = wqb; j = i - 1048576; }
  else                  { v = wo[i - 1835008]; dst = wob; j = i - 1835008; }
  ushort4 o;
  o.x = f2bf(v.x); o.y = f2bf(v.y); o.z = f2bf(v.z); o.w = f2bf(v.w);
  dst[j] = o;
}

// ---------------- GEMM1 + fused RoPE/scatter epilogue -----------------------
// 128x128 tile, BK=32. SINGLE-BARRIER 3-buffer pipeline (T3 minimum-2-phase,
// guide 5.5): per K-step only {vmcnt(4) -> s_barrier -> stage(kt+2) ->
// ds_read(kt) -> MFMA}. The old loop had TWO barriers + lgkmcnt(0) fence per
// step (m233: that structure's overhead ~72%). Safety: the start barrier of
// iter kt separates stage(buf[(kt+2)%3]) from all waves' reads of that same
// buffer at iter kt-1 (reads are MFMA-consumed -> drained before any wave
// passes the barrier). Stage->wait distance ~2 iters > HBM latency.
__global__ __launch_bounds__(256) void gemm1_fused(
    const __hip_bfloat16* __restrict__ A,
    const __hip_bfloat16* __restrict__ B,
    unsigned short* __restrict__ Qs,
    unsigned short* __restrict__ Ks,
    unsigned short* __restrict__ Vt,
    const float2* __restrict__ tab, int K) {
  __shared__ __align__(16) char lds[49152];  // 3 bufs x (8K A + 8K B)
  const int tid = threadIdx.x;
  const int lane = tid & 63;
  const int wave = tid >> 6;
  const int wm = (wave >> 1) * 64, wn = (wave & 1) * 64;
  const int g = lane >> 4, lr = lane & 15;
  const int m0 = blockIdx.y * 128, n0 = blockIdx.x * 128;
  f32x4 acc[4][4] = {};

  const size_t ldb = (size_t)K * 2;
  const int c0 = tid, c1 = tid + 256;
  const int r0 = c0 >> 2, cb0 = ((c0 & 3) * 16) ^ (((r0 >> 1) & 3) << 4);
  const int r1 = c1 >> 2, cb1 = ((c1 & 3) * 16) ^ (((r1 >> 1) & 3) << 4);
  const char* A0 = (const char*)(A + (size_t)m0 * K) + (size_t)r0 * ldb + cb0;
  const char* A1 = (const char*)(A + (size_t)m0 * K) + (size_t)r1 * ldb + cb1;
  const char* B0 = (const char*)(B + (size_t)n0 * K) + (size_t)r0 * ldb + cb0;
  const char* B1 = (const char*)(B + (size_t)n0 * K) + (size_t)r1 * ldb + cb1;

  auto stage = [&](int bo) {
    gl2lds16(A0, lds + bo + c0 * 16);
    gl2lds16(A1, lds + bo + c1 * 16);
    gl2lds16(B0, lds + bo + 8192 + c0 * 16);
    gl2lds16(B1, lds + bo + 8192 + c1 * 16);
    A0 += 64; A1 += 64; B0 += 64; B1 += 64;  // advance 32 k (64B)
  };

  stage(0);      // tile 0 -> buf 0
  stage(16384);  // tile 1 -> buf 1   (8 loads in flight)

  const int swz = ((lr >> 1) & 3) << 4;  // (row>>1)&3 == (lr>>1)&3
  const int NSTEP = K / 32;
  for (int kt = 0; kt < NSTEP; ++kt) {
    const int bo = (kt % 3) * 16384;
    if (kt + 1 < NSTEP) {
      asm volatile("s_waitcnt vmcnt(4)" ::: "memory");  // tile kt landed
    } else {
      asm volatile("s_waitcnt vmcnt(0)" ::: "memory");
    }
    asm volatile("s_barrier" ::: "memory");  // the ONLY barrier per K-step
    if (kt + 2 < NSTEP) stage(((kt + 2) % 3) * 16384);

    bf16x8 af[4], bfr[4];
#pragma unroll
    for (int i = 0; i < 4; ++i)
      af[i] = *(const bf16x8*)(lds + bo + (wm + i * 16 + lr) * 64 + ((g * 16) ^ swz));
#pragma unroll
    for (int i = 0; i < 4; ++i)
      bfr[i] = *(const bf16x8*)(lds + bo + 8192 + (wn + i * 16 + lr) * 64 + ((g * 16) ^ swz));
    __builtin_amdgcn_s_setprio(1);
#pragma unroll
    for (int i = 0; i < 4; ++i)
#pragma unroll
      for (int j = 0; j < 4; ++j)
        acc[i][j] = __builtin_amdgcn_mfma_f32_16x16x32_bf16(af[i], bfr[j], acc[i][j], 0, 0, 0);
    __builtin_amdgcn_s_setprio(0);
  }

  // ---- fused epilogue ----
  const int sel = n0 >> 10;  // 0 Q, 1 K, 2 V (uniform per block)
  if (sel <= 1) {
    const float qscale = (sel == 0) ? 0.125f * 1.44269504088896f : 1.0f;
    unsigned short* dst = (sel == 0) ? Qs : Ks;
#pragma unroll
    for (int j = 0; j < 4; ++j) {
      const int nn = (n0 + wn + j * 16 + lr) & 1023;
      const int h = nn >> 6, d = nn & 63;
      const float2* tabrow = tab + (d >> 1);
      const float sgn = (d & 1) ? 1.0f : -1.0f;
#pragma unroll
      for (int i = 0; i < 4; ++i) {
#pragma unroll
        for (int r = 0; r < 4; ++r) {
          const int m = m0 + wm + i * 16 + g * 4 + r;
          const int l = m & 2047, b = m >> 11;
          float own = acc[i][j][r];
          float part = __shfl_xor(own, 1);
          float2 cs = tabrow[l * 32];
          float out = fmaf(cs.x, own, sgn * cs.y * part) * qscale;
          dst[((size_t)((b * 16 + h) * 2048 + l)) * 64 + d] = f2bf(out);
        }
      }
    }
  } else {
    // V: no rotation; scatter to Vt[bh][d][perm(l)] (column-permuted, so the
    // attention PV B-frag needs no cross-lane moves). perm(l0+r)=perm(l0)+r.
#pragma unroll
    for (int j = 0; j < 4; ++j) {
      const int nn = (n0 + wn + j * 16 + lr) & 1023;
      const int h = nn >> 6, d = nn & 63;
#pragma unroll
      for (int i = 0; i < 4; ++i) {
        const int mb = m0 + wm + i * 16 + g * 4;
        const int l0 = mb & 2047, b = mb >> 11;
        const int pl = (l0 & ~31) + 8 * ((l0 & 15) >> 2) + 4 * ((l0 >> 4) & 1) + (l0 & 3);
        ushort4 v4;
        v4.x = f2bf(acc[i][j][0]); v4.y = f2bf(acc[i][j][1]);
        v4.z = f2bf(acc[i][j][2]); v4.w = f2bf(acc[i][j][3]);
        *(ushort4*)(Vt + ((size_t)((b * 16 + h) * 64 + d)) * 2048 + pl) = v4;
      }
    }
  }
}

// ---------------- GEMM2: 64x64 tile, single-barrier 3-buffer ----------------
__global__ __launch_bounds__(256) void gemm2_64(
    const __hip_bfloat16* __restrict__ A,
    const __hip_bfloat16* __restrict__ B,
    float* __restrict__ C, int M, int N, int K) {
  __shared__ __align__(16) char lds[24576];  // A: buf*4096, B: 12288+buf*4096
  const int tid = threadIdx.x, lane = tid & 63, w = tid >> 6;
  const int g = lane >> 4, lr = lane & 15;
  const int n0 = blockIdx.x * 64, m0 = blockIdx.y * 64;
  f32x4 acc[4] = {};

  const size_t ld = (size_t)K * 2;
  const int o16 = tid * 16;
  const int s = o16 ^ (((o16 >> 7) & 3) << 4);
  const int srow = s >> 6, scolb = s & 63;
  const char* Asrc = (const char*)(A + (size_t)m0 * K) + (size_t)srow * ld + scolb;
  const char* Bsrc = (const char*)(B + (size_t)n0 * K) + (size_t)srow * ld + scolb;

  auto stage = [&](int buf) {
    gl2lds16(Asrc, lds + buf * 4096 + o16);
    gl2lds16(Bsrc, lds + 12288 + buf * 4096 + o16);
    Asrc += 64; Bsrc += 64;
  };

  stage(0);  // tile 0
  stage(1);  // tile 1  (4 loads in flight)

  const int swz = ((lr >> 1) & 3) << 4;  // read-side swizzle
  const int NSTEP = K / 32;       // 32
  for (int kt = 0; kt < NSTEP; ++kt) {
    const int buf = kt % 3;
    if (kt + 1 < NSTEP) {
      asm volatile("s_waitcnt vmcnt(2)" ::: "memory");  // tile kt landed
    } else {
      asm volatile("s_waitcnt vmcnt(0)" ::: "memory");
    }
    asm volatile("s_barrier" ::: "memory");
    if (kt + 2 < NSTEP) stage((kt + 2) % 3);

    bf16x8 af = *(const bf16x8*)(lds + buf * 4096 + (w * 16 + lr) * 64 + ((g * 16) ^ swz));
    __builtin_amdgcn_s_setprio(1);
#pragma unroll
    for (int j = 0; j < 4; ++j) {
      bf16x8 bf = *(const bf16x8*)(lds + 12288 + buf * 4096 + (j * 16 + lr) * 64 + ((g * 16) ^ swz));
      acc[j] = __builtin_amdgcn_mfma_f32_16x16x32_bf16(af, bf, acc[j], 0, 0, 0);
    }
    __builtin_amdgcn_s_setprio(0);
  }

  // C/D layout: n = n0 + j*16 + lr, m = m0 + w*16 + g*4 + r.
#pragma unroll
  for (int j = 0; j < 4; ++j) {
    int n = n0 + j * 16 + lr;
#pragma unroll
    for (int r = 0; r < 4; ++r) {
      int m = m0 + w * 16 + g * 4 + r;
      C[(size_t)m * N + n] = acc[j][r];
    }
  }
}

// ---------------- Flash attention, split-K=2, P in registers ----------------
// (round-10 version, verbatim: 48.5us, MfmaUtil 31%, zero bank conflicts)
__global__ __launch_bounds__(256, 4) void attn_fwd(
    const __hip_bfloat16* __restrict__ Qs,
    const __hip_bfloat16* __restrict__ Ks,
    const __hip_bfloat16* __restrict__ Vt,
    float* __restrict__ Opart,
    float2* __restrict__ Ml) {
  constexpr int L = 2048;
  __shared__ __align__(16) char lds[32768];  // [0,16K) Kt x2, [16K,32K) Vt x2
  const int tid = threadIdx.x, lane = tid & 63, w = tid >> 6;
  const int g = lane >> 4, lr = lane & 15;
  const int blk = blockIdx.x;
  const int xcd = blk & 7, slot = blk >> 3;   // 128 slots per XCD
  const int bh = xcd * 4 + (slot >> 5);       // 4 bh per XCD
  const int rem = slot & 31;
  const int qt = rem >> 1, half = rem & 1;
  const int q0 = qt * 128 + w * 32 + lr;      // q-group 0 row; qg1 = q0+16
  const int kt0 = half * 16;

  const __hip_bfloat16* Qr = Qs + ((size_t)bh * L + q0) * 64;
  bf16x8 qf[2][2];
  qf[0][0] = *(const bf16x8*)(Qr + g * 8);
  qf[0][1] = *(const bf16x8*)(Qr + 32 + g * 8);
  qf[1][0] = *(const bf16x8*)(Qr + 16 * 64 + g * 8);
  qf[1][1] = *(const bf16x8*)(Qr + 16 * 64 + 32 + g * 8);

  bf16x8 onesf;
#pragma unroll
  for (int j = 0; j < 8; ++j) onesf[j] = (__bf16)1.0f;

  // LDS frag addressing (XOR-swizzled 128B rows):
  const int xmask = (lr & 7) << 4;
  const int loff0 = ((g * 16) ^ (xmask & 0x30)) + (xmask & 0x40);
  const int kb0 = lr * 128 + loff0;
  const int kb1 = kb0 ^ 64;

  // Staging: 2 K-chunks + 2 V-chunks (16B) per thread per tile.
  const int c0 = tid * 16, c1 = c0 + 4096;
  const int os0 = c0 ^ (((c0 >> 7) & 7) << 4);
  const int os1 = c1 ^ (((c1 >> 7) & 7) << 4);
  const char* Kb = (const char*)(Ks + (size_t)bh * L * 64) + (size_t)kt0 * 8192;
  const char* Vb = (const char*)(Vt + (size_t)bh * 64 * L) + kt0 * 128;
  const char* KsrcA = Kb + os0;
  const char* KsrcB = Kb + os1;
  const char* VsrcA = Vb + (size_t)(os0 >> 7) * (L * 2) + (os0 & 127);
  const char* VsrcB = Vb + (size_t)(os1 >> 7) * (L * 2) + (os1 & 127);

  auto stage = [&](int bo) {
    gl2lds16(KsrcA, lds + bo + c0);
    gl2lds16(KsrcB, lds + bo + c1);
    gl2lds16(VsrcA, lds + 16384 + bo + c0);
    gl2lds16(VsrcB, lds + 16384 + bo + c1);
    KsrcA += 8192; KsrcB += 8192; VsrcA += 128; VsrcB += 128;
  };

  f32x4 oacc[2][4] = {};
  f32x4 lacc[2] = {};
  float mrun[2] = {-1e30f, -1e30f};

  stage(0);  // prologue: 4 loads in flight

  for (int kt = 0; kt < 16; ++kt) {
    const int bo = (kt & 1) * 8192;
    if (kt + 1 < 16) {
      stage(bo ^ 8192);
      asm volatile("s_waitcnt vmcnt(4)" ::: "memory");  // cur tile's 4 done
    } else {
      asm volatile("s_waitcnt vmcnt(0)" ::: "memory");
    }
    __builtin_amdgcn_s_barrier();

    const char* Kc = lds + bo;
    const char* Vc = lds + 16384 + bo;

    // QK^T (swapped): sacc[qg][mf][r] = S^T[k=16mf+4g+r][q=lr], log2 units.
    f32x4 sacc[2][4] = {};
    __builtin_amdgcn_s_setprio(1);
#pragma unroll
    for (int mf = 0; mf < 4; ++mf) {
      bf16x8 a0 = *(const bf16x8*)(Kc + kb0 + mf * 2048);
      bf16x8 a1 = *(const bf16x8*)(Kc + kb1 + mf * 2048);
      sacc[0][mf] = __builtin_amdgcn_mfma_f32_16x16x32_bf16(a0, qf[0][0], sacc[0][mf], 0, 0, 0);
      sacc[0][mf] = __builtin_amdgcn_mfma_f32_16x16x32_bf16(a1, qf[0][1], sacc[0][mf], 0, 0, 0);
      sacc[1][mf] = __builtin_amdgcn_mfma_f32_16x16x32_bf16(a0, qf[1][0], sacc[1][mf], 0, 0, 0);
      sacc[1][mf] = __builtin_amdgcn_mfma_f32_16x16x32_bf16(a1, qf[1][1], sacc[1][mf], 0, 0, 0);
    }
    __builtin_amdgcn_s_setprio(0);

    // Softmax (log2 units). Per-lane local max (max3-shaped tree); full
    // cross-lane reduce + rescale only when some lane exceeds mrun+8.
#pragma unroll
    for (int qg = 0; qg < 2; ++qg) {
      float a0 = fmaxf(fmaxf(sacc[qg][0][0], sacc[qg][0][1]), sacc[qg][0][2]);
      float a1 = fmaxf(fmaxf(sacc[qg][0][3], sacc[qg][1][0]), sacc[qg][1][1]);
      float a2 = fmaxf(fmaxf(sacc[qg][1][2], sacc[qg][1][3]), sacc[qg][2][0]);
      float a3 = fmaxf(fmaxf(sacc[qg][2][1], sacc[qg][2][2]), sacc[qg][2][3]);
      float a4 = fmaxf(fmaxf(sacc[qg][3][0], sacc[qg][3][1]), sacc[qg][3][2]);
      float b0 = fmaxf(fmaxf(a0, a1), a2);
      float b1 = fmaxf(fmaxf(a3, a4), sacc[qg][3][3]);
      float lmax = fmaxf(b0, b1);
      if (__any(lmax > mrun[qg] + 8.0f)) {
        float tmax = fmaxf(lmax, __shfl_xor(lmax, 16));
        tmax = fmaxf(tmax, __shfl_xor(tmax, 32));
        float mnew = fmaxf(mrun[qg], tmax);
        float al = __builtin_amdgcn_exp2f(mrun[qg] - mnew);
        mrun[qg] = mnew;
        lacc[qg] *= al;
#pragma unroll
        for (int d = 0; d < 4; ++d) oacc[qg][d] = oacc[qg][d] * al;
      }
#pragma unroll
      for (int mf = 0; mf < 4; ++mf) {
        sacc[qg][mf][0] = __builtin_amdgcn_exp2f(sacc[qg][mf][0] - mrun[qg]);
        sacc[qg][mf][1] = __builtin_amdgcn_exp2f(sacc[qg][mf][1] - mrun[qg]);
        sacc[qg][mf][2] = __builtin_amdgcn_exp2f(sacc[qg][mf][2] - mrun[qg]);
        sacc[qg][mf][3] = __builtin_amdgcn_exp2f(sacc[qg][mf][3] - mrun[qg]);
      }
    }

    // PV: O^T = mfma(A=V-frag, B=P-frag). Vt's permuted k-layout means the
    // B-frag for slice ks is just {p[2ks][0..3], p[2ks+1][0..3]} in-lane.
    // lacc = mfma(ones, pf): every lane accumulates its q-row's sum(P).
#pragma unroll
    for (int ks = 0; ks < 2; ++ks) {
      bf16x8 pf[2];
#pragma unroll
      for (int qg = 0; qg < 2; ++qg) {
#pragma unroll
        for (int j = 0; j < 4; ++j) {
          pf[qg][j]     = (__bf16)sacc[qg][2 * ks][j];
          pf[qg][4 + j] = (__bf16)sacc[qg][2 * ks + 1][j];
        }
      }
      const int kb = ks ? kb1 : kb0;
      __builtin_amdgcn_s_setprio(1);
      lacc[0] = __builtin_amdgcn_mfma_f32_16x16x32_bf16(onesf, pf[0], lacc[0], 0, 0, 0);
      lacc[1] = __builtin_amdgcn_mfma_f32_16x16x32_bf16(onesf, pf[1], lacc[1], 0, 0, 0);
#pragma unroll
      for (int df = 0; df < 4; ++df) {
        bf16x8 a = *(const bf16x8*)(Vc + kb + df * 2048);
        oacc[0][df] = __builtin_amdgcn_mfma_f32_16x16x32_bf16(a, pf[0], oacc[0][df], 0, 0, 0);
        oacc[1][df] = __builtin_amdgcn_mfma_f32_16x16x32_bf16(a, pf[1], oacc[1][df], 0, 0, 0);
      }
      __builtin_amdgcn_s_setprio(0);
    }
    asm volatile("s_waitcnt lgkmcnt(0)" ::: "memory");
    __builtin_amdgcn_s_barrier();  // cur buffers free for next stage
  }

#pragma unroll
  for (int qg = 0; qg < 2; ++qg) {
    const size_t rowi = ((size_t)bh * L + q0 + qg * 16) * 2 + half;
    float* Od = Opart + rowi * 64;
#pragma unroll
    for (int df = 0; df < 4; ++df)
      *(f32x4*)(Od + df * 16 + g * 4) = oacc[qg][df];
    if (g == 0) {
      float2 ml; ml.x = mrun[qg]; ml.y = lacc[qg][0];
      Ml[rowi] = ml;
    }
  }
}

// ---------------- Split-K combine: Ob[b][l][h*64+d] = sum(Opart)/l ----------
__global__ __launch_bounds__(256) void attn_reduce(
    const float* __restrict__ Opart, const float2* __restrict__ Ml,
    unsigned short* __restrict__ Ob) {
  int t = blockIdx.x * 256 + threadIdx.x;
  int d = t & 63;
  int r = t >> 6;  // 0..65535 = bh*2048 + q
  float2 a = Ml[2 * r], b = Ml[2 * r + 1];
  float m = fmaxf(a.x, b.x);
  float w0 = __builtin_amdgcn_exp2f(a.x - m);
  float w1 = __builtin_amdgcn_exp2f(b.x - m);
  float l = a.y * w0 + b.y * w1;
  float o = Opart[(size_t)(2 * r) * 64 + d] * w0 + Opart[(size_t)(2 * r + 1) * 64 + d] * w1;
  float out = o / l;
  int bh = r >> 11, qq = r & 2047;
  Ob[(((size_t)(bh >> 4) * 2048 + qq)) * 1024 + (bh & 15) * 64 + d] = f2bf(out);
}

// ---------------- launch ----------------
extern "C" void kernel_launch(void* const* d_in, const int* in_sizes, int n_in,
                              void* d_out, int out_size, void* d_ws, size_t ws_size,
                              hipStream_t stream) {
  (void)in_sizes; (void)n_in; (void)out_size; (void)ws_size;
  const float* x    = (const float*)d_in[0];   // [2,2048,1024]
  const float* wqkv = (const float*)d_in[1];   // [3072,1024]
  const float* wout = (const float*)d_in[2];   // [1024,1024]

  char* ws = (char*)d_ws;
  // Workspace (66MB):
  //  [0..2M)   wob, [2..10M) Qsb/Ob, [10..18M) Ksb, [18..26M) Vtb,
  //  [26..58M) Opart, [50..58M) xb (dead before Opart tail written),
  //  [58..59M) Ml, [59..59.5M) RoPE table, [59.5..65.5M) wqb
  auto* wob   = (__hip_bfloat16*)(ws + ((size_t)0u  << 20));
  auto* Qsb   = (__hip_bfloat16*)(ws + ((size_t)2u  << 20));
  auto* Ob    = (__hip_bfloat16*)(ws + ((size_t)2u  << 20));
  auto* Ksb   = (__hip_bfloat16*)(ws + ((size_t)10u << 20));
  auto* Vtb   = (__hip_bfloat16*)(ws + ((size_t)18u << 20));
  auto* Opart = (float*)         (ws + ((size_t)26u << 20));
  auto* xb    = (__hip_bfloat16*)(ws + ((size_t)50u << 20));
  auto* Mlp   = (float2*)        (ws + ((size_t)58u << 20));
  auto* tab   = (float2*)        (ws + ((size_t)59u << 20));
  auto* wqb   = (__hip_bfloat16*)(ws + (((size_t)59u << 20) + ((size_t)1u << 19)));

  cvt_all<<<8448, 256, 0, stream>>>((const float4*)x, (const float4*)wqkv,
                                    (const float4*)wout,
                                    (ushort4*)xb, (ushort4*)wqb, (ushort4*)wob,
                                    tab);
  gemm1_fused<<<dim3(24, 32), 256, 0, stream>>>(xb, wqb,
                                                (unsigned short*)Qsb,
                                                (unsigned short*)Ksb,
                                                (unsigned short*)Vtb,
                                                tab, 1024);
  attn_fwd<<<1024, 256, 0, stream>>>(Qsb, Ksb, Vtb, Opart, Mlp);
  attn_reduce<<<16384, 256, 0, stream>>>(Opart, Mlp, (unsigned short*)Ob);
  gemm2_64<<<dim3(16, 64), 256, 0, stream>>>(Ob, wob, (float*)d_out,
                                             4096, 1024, 1024);
}

// Round 18
// 129.247 us; speedup vs baseline: 1.0634x; 1.0128x over previous
//
#include <hip/hip_runtime.h>
#include <hip/hip_bf16.h>
#include <stdint.h>

// Problem constants: B=2, L=2048, D=1024, H=16, hd=64, scale=1/8 (log2e-folded).

typedef __bf16 bf16x8 __attribute__((ext_vector_type(8)));
typedef float f32x4 __attribute__((ext_vector_type(4)));

__device__ __forceinline__ unsigned short f2bf(float f) {
  union { float f; unsigned int u; } v; v.f = f;
  unsigned int r = v.u + 0x7FFFu + ((v.u >> 16) & 1u);  // RNE
  return (unsigned short)(r >> 16);
}
__device__ __forceinline__ float b2f(unsigned short u) {
  union { unsigned int u; float f; } v; v.u = ((unsigned int)u) << 16;
  return v.f;
}

__device__ __forceinline__ void gl2lds16(const void* gptr, void* lptr) {
  __builtin_amdgcn_global_load_lds(
      (const __attribute__((address_space(1))) unsigned int*)gptr,
      (__attribute__((address_space(3))) unsigned int*)lptr, 16, 0, 0);
}

// ------- fp32 -> bf16 conversion (x | W_qkv | W_out) + RoPE cos/sin table ---
__global__ void cvt_all(const float4* __restrict__ x,
                        const float4* __restrict__ wq,
                        const float4* __restrict__ wo,
                        ushort4* __restrict__ xb,
                        ushort4* __restrict__ wqb,
                        ushort4* __restrict__ wob,
                        float2* __restrict__ tab) {
  int i = blockIdx.x * 256 + threadIdx.x;
  if (i >= 2097152) {
    int t = i - 2097152;         // 0..65535 = l*32 + fi
    int l = t >> 5, fi = t & 31;
    float inv_freq = powf(10000.0f, -(float)fi / 32.0f);
    float s, c;
    sincosf((float)l * inv_freq, &s, &c);
    tab[t] = make_float2(c, s);
    return;
  }
  float4 v; ushort4* dst; int j;
  if (i < 1048576)      { v = x[i];            dst = xb;  j = i; }
  else if (i < 1835008) { v = wq[i - 1048576]; dst = wqb; j = i - 1048576; }
  else                  { v = wo[i - 1835008]; dst = wob; j = i - 1835008; }
  ushort4 o;
  o.x = f2bf(v.x); o.y = f2bf(v.y); o.z = f2bf(v.z); o.w = f2bf(v.w);
  dst[j] = o;
}

// ---------------- GEMM1 + fused RoPE/scatter epilogue -----------------------
// K-loop: single-barrier 3-buffer pipeline (r17, proven correct).
// EPILOGUE REWRITE (r18): the old Q/K path did 64 shfl + 64 scattered 8B tab
// gathers + 64 scattered 2B stores per thread (~20us of the 60us kernel).
// Now: phase 1 writes raw bf16 results to a swizzled LDS tile [128m][16x16B]
// (chunk ^= m&7; conflict-free), phase 2 reads back 16B chunks per (l,h) row,
// loads cos/sin CONTIGUOUSLY (tab + l*32 + k*4, 32B), applies RoPE in-register
// (pairs adjacent after repack, no shfl), stores dwordx4 with 8 lanes forming
// 128B-contiguous runs (1KB/wave-instruction).
__global__ __launch_bounds__(256) void gemm1_fused(
    const __hip_bfloat16* __restrict__ A,
    const __hip_bfloat16* __restrict__ B,
    unsigned short* __restrict__ Qs,
    unsigned short* __restrict__ Ks,
    unsigned short* __restrict__ Vt,
    const float2* __restrict__ tab, int K) {
  __shared__ __align__(16) char lds[49152];  // 3 bufs x (8K A + 8K B)
  const int tid = threadIdx.x;
  const int lane = tid & 63;
  const int wave = tid >> 6;
  const int wm = (wave >> 1) * 64, wn = (wave & 1) * 64;
  const int g = lane >> 4, lr = lane & 15;
  const int m0 = blockIdx.y * 128, n0 = blockIdx.x * 128;
  f32x4 acc[4][4] = {};

  const size_t ldb = (size_t)K * 2;
  const int c0 = tid, c1 = tid + 256;
  const int r0 = c0 >> 2, cb0 = ((c0 & 3) * 16) ^ (((r0 >> 1) & 3) << 4);
  const int r1 = c1 >> 2, cb1 = ((c1 & 3) * 16) ^ (((r1 >> 1) & 3) << 4);
  const char* A0 = (const char*)(A + (size_t)m0 * K) + (size_t)r0 * ldb + cb0;
  const char* A1 = (const char*)(A + (size_t)m0 * K) + (size_t)r1 * ldb + cb1;
  const char* B0 = (const char*)(B + (size_t)n0 * K) + (size_t)r0 * ldb + cb0;
  const char* B1 = (const char*)(B + (size_t)n0 * K) + (size_t)r1 * ldb + cb1;

  auto stage = [&](int bo) {
    gl2lds16(A0, lds + bo + c0 * 16);
    gl2lds16(A1, lds + bo + c1 * 16);
    gl2lds16(B0, lds + bo + 8192 + c0 * 16);
    gl2lds16(B1, lds + bo + 8192 + c1 * 16);
    A0 += 64; A1 += 64; B0 += 64; B1 += 64;  // advance 32 k (64B)
  };

  stage(0);      // tile 0 -> buf 0
  stage(16384);  // tile 1 -> buf 1   (8 loads in flight)

  const int swz = ((lr >> 1) & 3) << 4;  // (row>>1)&3 == (lr>>1)&3
  const int NSTEP = K / 32;
  for (int kt = 0; kt < NSTEP; ++kt) {
    const int bo = (kt % 3) * 16384;
    if (kt + 1 < NSTEP) {
      asm volatile("s_waitcnt vmcnt(4)" ::: "memory");  // tile kt landed
    } else {
      asm volatile("s_waitcnt vmcnt(0)" ::: "memory");
    }
    asm volatile("s_barrier" ::: "memory");  // the ONLY barrier per K-step
    if (kt + 2 < NSTEP) stage(((kt + 2) % 3) * 16384);

    bf16x8 af[4], bfr[4];
#pragma unroll
    for (int i = 0; i < 4; ++i)
      af[i] = *(const bf16x8*)(lds + bo + (wm + i * 16 + lr) * 64 + ((g * 16) ^ swz));
#pragma unroll
    for (int i = 0; i < 4; ++i)
      bfr[i] = *(const bf16x8*)(lds + bo + 8192 + (wn + i * 16 + lr) * 64 + ((g * 16) ^ swz));
    __builtin_amdgcn_s_setprio(1);
#pragma unroll
    for (int i = 0; i < 4; ++i)
#pragma unroll
      for (int j = 0; j < 4; ++j)
        acc[i][j] = __builtin_amdgcn_mfma_f32_16x16x32_bf16(af[i], bfr[j], acc[i][j], 0, 0, 0);
    __builtin_amdgcn_s_setprio(0);
  }

  // ---- fused epilogue ----
  const int sel = n0 >> 10;  // 0 Q, 1 K, 2 V (uniform per block)
  if (sel <= 1) {
    // Phase 1: raw bf16 results -> swizzled LDS tile [128m][16 chunks x 16B].
    asm volatile("s_waitcnt lgkmcnt(0)" ::: "memory");
    asm volatile("s_barrier" ::: "memory");  // all loop reads done; LDS free
#pragma unroll
    for (int j = 0; j < 4; ++j) {
      const int nl = wn + j * 16 + lr;
      const int chunkb = nl >> 3, sub = (nl & 7) * 2;
#pragma unroll
      for (int i = 0; i < 4; ++i) {
#pragma unroll
        for (int r = 0; r < 4; ++r) {
          const int ml = wm + i * 16 + g * 4 + r;
          *(unsigned short*)(lds + ml * 256 + ((chunkb ^ (ml & 7)) * 16) + sub) =
              f2bf(acc[i][j][r]);
        }
      }
    }
    asm volatile("s_waitcnt lgkmcnt(0)" ::: "memory");
    asm volatile("s_barrier" ::: "memory");

    // Phase 2: read back per (l,h) row, RoPE in-register, coalesced stores.
    const float qs = (sel == 0) ? 0.125f * 1.44269504088896f : 1.0f;
    unsigned short* dstp = (sel == 0) ? Qs : Ks;
    const int hb = (n0 & 1023) >> 6;      // head base (even)
    const int lbase = m0 & 2047, bb = m0 >> 11;
    const int k = tid & 7;                // 16B chunk = d range k*8..k*8+8
#pragma unroll
    for (int p = 0; p < 8; ++p) {
      const int u = (tid >> 3) + 32 * p;  // u = h2*128 + l_loc
      const int lloc = u & 127, h2 = u >> 7;
      union { uint4 u4; unsigned short us[8]; } in;
      in.u4 = *(const uint4*)(lds + lloc * 256 + (((h2 * 8 + k) ^ (lloc & 7)) * 16));
      const int l = lbase + lloc;
      const float4* t4 = (const float4*)(tab + (size_t)l * 32 + k * 4);
      const float4 cA = t4[0], cB = t4[1];  // (c,s) for freq k*4.. k*4+3
      const float x0 = b2f(in.us[0]), x1 = b2f(in.us[1]);
      const float x2 = b2f(in.us[2]), x3 = b2f(in.us[3]);
      const float x4 = b2f(in.us[4]), x5 = b2f(in.us[5]);
      const float x6 = b2f(in.us[6]), x7 = b2f(in.us[7]);
      union { unsigned short us[8]; uint4 u4; } o;
      o.us[0] = f2bf((cA.x * x0 - cA.y * x1) * qs);
      o.us[1] = f2bf((cA.y * x0 + cA.x * x1) * qs);
      o.us[2] = f2bf((cA.z * x2 - cA.w * x3) * qs);
      o.us[3] = f2bf((cA.w * x2 + cA.z * x3) * qs);
      o.us[4] = f2bf((cB.x * x4 - cB.y * x5) * qs);
      o.us[5] = f2bf((cB.y * x4 + cB.x * x5) * qs);
      o.us[6] = f2bf((cB.z * x6 - cB.w * x7) * qs);
      o.us[7] = f2bf((cB.w * x6 + cB.z * x7) * qs);
      *(uint4*)(dstp + ((size_t)((bb * 16 + hb + h2) * 2048 + l)) * 64 + k * 8) = o.u4;
    }
  } else {
    // V: no rotation; scatter to Vt[bh][d][perm(l)] (column-permuted, so the
    // attention PV B-frag needs no cross-lane moves). perm(l0+r)=perm(l0)+r.
#pragma unroll
    for (int j = 0; j < 4; ++j) {
      const int nn = (n0 + wn + j * 16 + lr) & 1023;
      const int h = nn >> 6, d = nn & 63;
#pragma unroll
      for (int i = 0; i < 4; ++i) {
        const int mb = m0 + wm + i * 16 + g * 4;
        const int l0 = mb & 2047, b = mb >> 11;
        const int pl = (l0 & ~31) + 8 * ((l0 & 15) >> 2) + 4 * ((l0 >> 4) & 1) + (l0 & 3);
        ushort4 v4;
        v4.x = f2bf(acc[i][j][0]); v4.y = f2bf(acc[i][j][1]);
        v4.z = f2bf(acc[i][j][2]); v4.w = f2bf(acc[i][j][3]);
        *(ushort4*)(Vt + ((size_t)((b * 16 + h) * 64 + d)) * 2048 + pl) = v4;
      }
    }
  }
}

// ---------------- GEMM2: 64x64 tile, single-barrier 3-buffer ----------------
__global__ __launch_bounds__(256) void gemm2_64(
    const __hip_bfloat16* __restrict__ A,
    const __hip_bfloat16* __restrict__ B,
    float* __restrict__ C, int M, int N, int K) {
  __shared__ __align__(16) char lds[24576];  // A: buf*4096, B: 12288+buf*4096
  const int tid = threadIdx.x, lane = tid & 63, w = tid >> 6;
  const int g = lane >> 4, lr = lane & 15;
  const int n0 = blockIdx.x * 64, m0 = blockIdx.y * 64;
  f32x4 acc[4] = {};

  const size_t ld = (size_t)K * 2;
  const int o16 = tid * 16;
  const int s = o16 ^ (((o16 >> 7) & 3) << 4);
  const int srow = s >> 6, scolb = s & 63;
  const char* Asrc = (const char*)(A + (size_t)m0 * K) + (size_t)srow * ld + scolb;
  const char* Bsrc = (const char*)(B + (size_t)n0 * K) + (size_t)srow * ld + scolb;

  auto stage = [&](int buf) {
    gl2lds16(Asrc, lds + buf * 4096 + o16);
    gl2lds16(Bsrc, lds + 12288 + buf * 4096 + o16);
    Asrc += 64; Bsrc += 64;
  };

  stage(0);  // tile 0
  stage(1);  // tile 1  (4 loads in flight)

  const int swz = ((lr >> 1) & 3) << 4;  // read-side swizzle
  const int NSTEP = K / 32;       // 32
  for (int kt = 0; kt < NSTEP; ++kt) {
    const int buf = kt % 3;
    if (kt + 1 < NSTEP) {
      asm volatile("s_waitcnt vmcnt(2)" ::: "memory");  // tile kt landed
    } else {
      asm volatile("s_waitcnt vmcnt(0)" ::: "memory");
    }
    asm volatile("s_barrier" ::: "memory");
    if (kt + 2 < NSTEP) stage((kt + 2) % 3);

    bf16x8 af = *(const bf16x8*)(lds + buf * 4096 + (w * 16 + lr) * 64 + ((g * 16) ^ swz));
    __builtin_amdgcn_s_setprio(1);
#pragma unroll
    for (int j = 0; j < 4; ++j) {
      bf16x8 bf = *(const bf16x8*)(lds + 12288 + buf * 4096 + (j * 16 + lr) * 64 + ((g * 16) ^ swz));
      acc[j] = __builtin_amdgcn_mfma_f32_16x16x32_bf16(af, bf, acc[j], 0, 0, 0);
    }
    __builtin_amdgcn_s_setprio(0);
  }

  // C/D layout: n = n0 + j*16 + lr, m = m0 + w*16 + g*4 + r.
#pragma unroll
  for (int j = 0; j < 4; ++j) {
    int n = n0 + j * 16 + lr;
#pragma unroll
    for (int r = 0; r < 4; ++r) {
      int m = m0 + w * 16 + g * 4 + r;
      C[(size_t)m * N + n] = acc[j][r];
    }
  }
}

// ---------------- Flash attention, split-K=2, P in registers ----------------
// (round-10 version, verbatim: 48.5us, MfmaUtil 31%, zero bank conflicts)
__global__ __launch_bounds__(256, 4) void attn_fwd(
    const __hip_bfloat16* __restrict__ Qs,
    const __hip_bfloat16* __restrict__ Ks,
    const __hip_bfloat16* __restrict__ Vt,
    float* __restrict__ Opart,
    float2* __restrict__ Ml) {
  constexpr int L = 2048;
  __shared__ __align__(16) char lds[32768];  // [0,16K) Kt x2, [16K,32K) Vt x2
  const int tid = threadIdx.x, lane = tid & 63, w = tid >> 6;
  const int g = lane >> 4, lr = lane & 15;
  const int blk = blockIdx.x;
  const int xcd = blk & 7, slot = blk >> 3;   // 128 slots per XCD
  const int bh = xcd * 4 + (slot >> 5);       // 4 bh per XCD
  const int rem = slot & 31;
  const int qt = rem >> 1, half = rem & 1;
  const int q0 = qt * 128 + w * 32 + lr;      // q-group 0 row; qg1 = q0+16
  const int kt0 = half * 16;

  const __hip_bfloat16* Qr = Qs + ((size_t)bh * L + q0) * 64;
  bf16x8 qf[2][2];
  qf[0][0] = *(const bf16x8*)(Qr + g * 8);
  qf[0][1] = *(const bf16x8*)(Qr + 32 + g * 8);
  qf[1][0] = *(const bf16x8*)(Qr + 16 * 64 + g * 8);
  qf[1][1] = *(const bf16x8*)(Qr + 16 * 64 + 32 + g * 8);

  bf16x8 onesf;
#pragma unroll
  for (int j = 0; j < 8; ++j) onesf[j] = (__bf16)1.0f;

  // LDS frag addressing (XOR-swizzled 128B rows):
  const int xmask = (lr & 7) << 4;
  const int loff0 = ((g * 16) ^ (xmask & 0x30)) + (xmask & 0x40);
  const int kb0 = lr * 128 + loff0;
  const int kb1 = kb0 ^ 64;

  // Staging: 2 K-chunks + 2 V-chunks (16B) per thread per tile.
  const int c0 = tid * 16, c1 = c0 + 4096;
  const int os0 = c0 ^ (((c0 >> 7) & 7) << 4);
  const int os1 = c1 ^ (((c1 >> 7) & 7) << 4);
  const char* Kb = (const char*)(Ks + (size_t)bh * L * 64) + (size_t)kt0 * 8192;
  const char* Vb = (const char*)(Vt + (size_t)bh * 64 * L) + kt0 * 128;
  const char* KsrcA = Kb + os0;
  const char* KsrcB = Kb + os1;
  const char* VsrcA = Vb + (size_t)(os0 >> 7) * (L * 2) + (os0 & 127);
  const char* VsrcB = Vb + (size_t)(os1 >> 7) * (L * 2) + (os1 & 127);

  auto stage = [&](int bo) {
    gl2lds16(KsrcA, lds + bo + c0);
    gl2lds16(KsrcB, lds + bo + c1);
    gl2lds16(VsrcA, lds + 16384 + bo + c0);
    gl2lds16(VsrcB, lds + 16384 + bo + c1);
    KsrcA += 8192; KsrcB += 8192; VsrcA += 128; VsrcB += 128;
  };

  f32x4 oacc[2][4] = {};
  f32x4 lacc[2] = {};
  float mrun[2] = {-1e30f, -1e30f};

  stage(0);  // prologue: 4 loads in flight

  for (int kt = 0; kt < 16; ++kt) {
    const int bo = (kt & 1) * 8192;
    if (kt + 1 < 16) {
      stage(bo ^ 8192);
      asm volatile("s_waitcnt vmcnt(4)" ::: "memory");  // cur tile's 4 done
    } else {
      asm volatile("s_waitcnt vmcnt(0)" ::: "memory");
    }
    __builtin_amdgcn_s_barrier();

    const char* Kc = lds + bo;
    const char* Vc = lds + 16384 + bo;

    // QK^T (swapped): sacc[qg][mf][r] = S^T[k=16mf+4g+r][q=lr], log2 units.
    f32x4 sacc[2][4] = {};
    __builtin_amdgcn_s_setprio(1);
#pragma unroll
    for (int mf = 0; mf < 4; ++mf) {
      bf16x8 a0 = *(const bf16x8*)(Kc + kb0 + mf * 2048);
      bf16x8 a1 = *(const bf16x8*)(Kc + kb1 + mf * 2048);
      sacc[0][mf] = __builtin_amdgcn_mfma_f32_16x16x32_bf16(a0, qf[0][0], sacc[0][mf], 0, 0, 0);
      sacc[0][mf] = __builtin_amdgcn_mfma_f32_16x16x32_bf16(a1, qf[0][1], sacc[0][mf], 0, 0, 0);
      sacc[1][mf] = __builtin_amdgcn_mfma_f32_16x16x32_bf16(a0, qf[1][0], sacc[1][mf], 0, 0, 0);
      sacc[1][mf] = __builtin_amdgcn_mfma_f32_16x16x32_bf16(a1, qf[1][1], sacc[1][mf], 0, 0, 0);
    }
    __builtin_amdgcn_s_setprio(0);

    // Softmax (log2 units). Per-lane local max (max3-shaped tree); full
    // cross-lane reduce + rescale only when some lane exceeds mrun+8.
#pragma unroll
    for (int qg = 0; qg < 2; ++qg) {
      float a0 = fmaxf(fmaxf(sacc[qg][0][0], sacc[qg][0][1]), sacc[qg][0][2]);
      float a1 = fmaxf(fmaxf(sacc[qg][0][3], sacc[qg][1][0]), sacc[qg][1][1]);
      float a2 = fmaxf(fmaxf(sacc[qg][1][2], sacc[qg][1][3]), sacc[qg][2][0]);
      float a3 = fmaxf(fmaxf(sacc[qg][2][1], sacc[qg][2][2]), sacc[qg][2][3]);
      float a4 = fmaxf(fmaxf(sacc[qg][3][0], sacc[qg][3][1]), sacc[qg][3][2]);
      float b0 = fmaxf(fmaxf(a0, a1), a2);
      float b1 = fmaxf(fmaxf(a3, a4), sacc[qg][3][3]);
      float lmax = fmaxf(b0, b1);
      if (__any(lmax > mrun[qg] + 8.0f)) {
        float tmax = fmaxf(lmax, __shfl_xor(lmax, 16));
        tmax = fmaxf(tmax, __shfl_xor(tmax, 32));
        float mnew = fmaxf(mrun[qg], tmax);
        float al = __builtin_amdgcn_exp2f(mrun[qg] - mnew);
        mrun[qg] = mnew;
        lacc[qg] *= al;
#pragma unroll
        for (int d = 0; d < 4; ++d) oacc[qg][d] = oacc[qg][d] * al;
      }
#pragma unroll
      for (int mf = 0; mf < 4; ++mf) {
        sacc[qg][mf][0] = __builtin_amdgcn_exp2f(sacc[qg][mf][0] - mrun[qg]);
        sacc[qg][mf][1] = __builtin_amdgcn_exp2f(sacc[qg][mf][1] - mrun[qg]);
        sacc[qg][mf][2] = __builtin_amdgcn_exp2f(sacc[qg][mf][2] - mrun[qg]);
        sacc[qg][mf][3] = __builtin_amdgcn_exp2f(sacc[qg][mf][3] - mrun[qg]);
      }
    }

    // PV: O^T = mfma(A=V-frag, B=P-frag). Vt's permuted k-layout means the
    // B-frag for slice ks is just {p[2ks][0..3], p[2ks+1][0..3]} in-lane.
    // lacc = mfma(ones, pf): every lane accumulates its q-row's sum(P).
#pragma unroll
    for (int ks = 0; ks < 2; ++ks) {
      bf16x8 pf[2];
#pragma unroll
      for (int qg = 0; qg < 2; ++qg) {
#pragma unroll
        for (int j = 0; j < 4; ++j) {
          pf[qg][j]     = (__bf16)sacc[qg][2 * ks][j];
          pf[qg][4 + j] = (__bf16)sacc[qg][2 * ks + 1][j];
        }
      }
      const int kb = ks ? kb1 : kb0;
      __builtin_amdgcn_s_setprio(1);
      lacc[0] = __builtin_amdgcn_mfma_f32_16x16x32_bf16(onesf, pf[0], lacc[0], 0, 0, 0);
      lacc[1] = __builtin_amdgcn_mfma_f32_16x16x32_bf16(onesf, pf[1], lacc[1], 0, 0, 0);
#pragma unroll
      for (int df = 0; df < 4; ++df) {
        bf16x8 a = *(const bf16x8*)(Vc + kb + df * 2048);
        oacc[0][df] = __builtin_amdgcn_mfma_f32_16x16x32_bf16(a, pf[0], oacc[0][df], 0, 0, 0);
        oacc[1][df] = __builtin_amdgcn_mfma_f32_16x16x32_bf16(a, pf[1], oacc[1][df], 0, 0, 0);
      }
      __builtin_amdgcn_s_setprio(0);
    }
    asm volatile("s_waitcnt lgkmcnt(0)" ::: "memory");
    __builtin_amdgcn_s_barrier();  // cur buffers free for next stage
  }

#pragma unroll
  for (int qg = 0; qg < 2; ++qg) {
    const size_t rowi = ((size_t)bh * L + q0 + qg * 16) * 2 + half;
    float* Od = Opart + rowi * 64;
#pragma unroll
    for (int df = 0; df < 4; ++df)
      *(f32x4*)(Od + df * 16 + g * 4) = oacc[qg][df];
    if (g == 0) {
      float2 ml; ml.x = mrun[qg]; ml.y = lacc[qg][0];
      Ml[rowi] = ml;
    }
  }
}

// ---------------- Split-K combine: Ob[b][l][h*64+d] = sum(Opart)/l ----------
__global__ __launch_bounds__(256) void attn_reduce(
    const float* __restrict__ Opart, const float2* __restrict__ Ml,
    unsigned short* __restrict__ Ob) {
  int t = blockIdx.x * 256 + threadIdx.x;
  int d = t & 63;
  int r = t >> 6;  // 0..65535 = bh*2048 + q
  float2 a = Ml[2 * r], b = Ml[2 * r + 1];
  float m = fmaxf(a.x, b.x);
  float w0 = __builtin_amdgcn_exp2f(a.x - m);
  float w1 = __builtin_amdgcn_exp2f(b.x - m);
  float l = a.y * w0 + b.y * w1;
  float o = Opart[(size_t)(2 * r) * 64 + d] * w0 + Opart[(size_t)(2 * r + 1) * 64 + d] * w1;
  float out = o / l;
  int bh = r >> 11, qq = r & 2047;
  Ob[(((size_t)(bh >> 4) * 2048 + qq)) * 1024 + (bh & 15) * 64 + d] = f2bf(out);
}

// ---------------- launch ----------------
extern "C" void kernel_launch(void* const* d_in, const int* in_sizes, int n_in,
                              void* d_out, int out_size, void* d_ws, size_t ws_size,
                              hipStream_t stream) {
  (void)in_sizes; (void)n_in; (void)out_size; (void)ws_size;
  const float* x    = (const float*)d_in[0];   // [2,2048,1024]
  const float* wqkv = (const float*)d_in[1];   // [3072,1024]
  const float* wout = (const float*)d_in[2];   // [1024,1024]

  char* ws = (char*)d_ws;
  // Workspace (66MB):
  //  [0..2M)   wob, [2..10M) Qsb/Ob, [10..18M) Ksb, [18..26M) Vtb,
  //  [26..58M) Opart, [50..58M) xb (dead before Opart tail written),
  //  [58..59M) Ml, [59..59.5M) RoPE table, [59.5..65.5M) wqb
  auto* wob   = (__hip_bfloat16*)(ws + ((size_t)0u  << 20));
  auto* Qsb   = (__hip_bfloat16*)(ws + ((size_t)2u  << 20));
  auto* Ob    = (__hip_bfloat16*)(ws + ((size_t)2u  << 20));
  auto* Ksb   = (__hip_bfloat16*)(ws + ((size_t)10u << 20));
  auto* Vtb   = (__hip_bfloat16*)(ws + ((size_t)18u << 20));
  auto* Opart = (float*)         (ws + ((size_t)26u << 20));
  auto* xb    = (__hip_bfloat16*)(ws + ((size_t)50u << 20));
  auto* Mlp   = (float2*)        (ws + ((size_t)58u << 20));
  auto* tab   = (float2*)        (ws + ((size_t)59u << 20));
  auto* wqb   = (__hip_bfloat16*)(ws + (((size_t)59u << 20) + ((size_t)1u << 19)));

  cvt_all<<<8448, 256, 0, stream>>>((const float4*)x, (const float4*)wqkv,
                                    (const float4*)wout,
                                    (ushort4*)xb, (ushort4*)wqb, (ushort4*)wob,
                                    tab);
  gemm1_fused<<<dim3(24, 32), 256, 0, stream>>>(xb, wqb,
                                                (unsigned short*)Qsb,
                                                (unsigned short*)Ksb,
                                                (unsigned short*)Vtb,
                                                tab, 1024);
  attn_fwd<<<1024, 256, 0, stream>>>(Qsb, Ksb, Vtb, Opart, Mlp);
  attn_reduce<<<16384, 256, 0, stream>>>(Opart, Mlp, (unsigned short*)Ob);
  gemm2_64<<<dim3(16, 64), 256, 0, stream>>>(Ob, wob, (float*)d_out,
                                             4096, 1024, 1024);
}